// Round 2
// baseline (941.299 us; speedup 1.0000x reference)
//
#include <hip/hip_runtime.h>
#include <hip/hip_bf16.h>

// Problem: B=2, C=256, H=W=D=16 -> N=4096, nh=8, dh=32. ALL float32 I/O.
// KEY ALGORITHMIC FACT: in the reference, x_sa (sparse self-attention path,
// top-k, index_sample, W_out, b_out, v_sa) is DEAD CODE — epa = x_ca only.
// Live pipeline: qkv gemm (3/4 of cols) -> l2norm(q,k over N) -> 32x32
// cross-attn per (b,h) -> W_out2 gemm + residual -> 3^3 conv (implicit GEMM,
// K=6912) -> per-batch mean/var norm -> +attn -> leaky relu.

#define B_ 2
#define C_ 256
#define N_ 4096
#define NH 8

// ---- workspace layout (floats) ----
#define OFF_T   0                          // [B][768][N] qkv_t fp32 (aliased as conv-out Y later)
#define SZ_T    (B_*768*N_)                // 6,291,456
#define OFF_A   (OFF_T + SZ_T)             // attn_ca [B][8][32][32]
#define SZ_A    (B_*NH*32*32)
#define OFF_XCA (OFF_A + SZ_A)             // [B][C][N]
#define SZ_CN   (B_*C_*N_)
#define OFF_ATT (OFF_XCA + SZ_CN)          // [B][C][N]
#define OFF_WT  (OFF_ATT + SZ_CN)          // conv_w transposed [t=27][ci=256][co=256] fp32
#define SZ_WT   (27*C_*C_)
#define OFF_RED (OFF_WT + SZ_WT)           // [B][64][2] partial sums
#define OFF_MU  (OFF_RED + B_*64*2)        // [B][2]: mu, rstd

// ---------------- weight transpose for conv: WT[t][ci][co] = conv_w[co][ci][t]
__global__ __launch_bounds__(256) void k_prep_w(const float* __restrict__ CW, float* __restrict__ WT) {
    int o = blockIdx.x * 256 + threadIdx.x;          // 27*256*256 = 1,769,472
    int co = o & 255, ci = (o >> 8) & 255, t = o >> 16;
    WT[o] = CW[((size_t)co * 256 + ci) * 27 + t];
}

// ---------------- QKV gemm: T[b][j][n] = sum_c Wq[c][j] * x[b][c][n], j<768
__global__ __launch_bounds__(256) void k_gemm_qkv(const float* __restrict__ Wq, const float* __restrict__ X,
                                                  float* __restrict__ T) {
    __shared__ float As[16][64], Bs[16][64];
    int n0 = blockIdx.x * 64, m0 = blockIdx.y * 64, b = blockIdx.z;
    int tid = threadIdx.x, tm = tid & 15, tn = tid >> 4;
    float acc[4][4] = {};
    const float* Xb = X + (size_t)b * C_ * N_;
    for (int c0 = 0; c0 < 256; c0 += 16) {
#pragma unroll
        for (int i = 0; i < 4; ++i) {
            int e = tid + 256 * i; int kk = e >> 6, m = e & 63;
            As[kk][m] = Wq[(size_t)(c0 + kk) * 1024 + m0 + m];   // coalesced in j
            Bs[kk][m] = Xb[(size_t)(c0 + kk) * N_ + n0 + m];     // coalesced in n
        }
        __syncthreads();
#pragma unroll
        for (int kk = 0; kk < 16; ++kk) {
            float4 a = *(const float4*)&As[kk][tm * 4];
            float4 bv = *(const float4*)&Bs[kk][tn * 4];
            float av[4] = {a.x, a.y, a.z, a.w}, bb[4] = {bv.x, bv.y, bv.z, bv.w};
#pragma unroll
            for (int i = 0; i < 4; ++i)
#pragma unroll
                for (int j = 0; j < 4; ++j) acc[i][j] += av[i] * bb[j];
        }
        __syncthreads();
    }
    float* Tb = T + ((size_t)b * 768 + m0) * N_ + n0;
#pragma unroll
    for (int i = 0; i < 4; ++i) {
        float4 st = make_float4(acc[i][0], acc[i][1], acc[i][2], acc[i][3]);
        *(float4*)&Tb[(size_t)(tm * 4 + i) * N_ + tn * 4] = st;
    }
}

// ---------------- l2norm over n for rows j in [0,512) (q and k)
__global__ __launch_bounds__(256) void k_l2norm(float* __restrict__ T) {
    int bj = blockIdx.x; int b = bj >> 9, j = bj & 511;
    float* row = T + ((size_t)b * 768 + j) * N_;
    float s = 0.f;
    for (int u = threadIdx.x * 4; u < N_; u += 1024) {
        float4 v = *(const float4*)&row[u];
        s += v.x * v.x + v.y * v.y + v.z * v.z + v.w * v.w;
    }
#pragma unroll
    for (int off = 32; off; off >>= 1) s += __shfl_down(s, off);
    __shared__ float rs[4]; __shared__ float rtot;
    int lane = threadIdx.x & 63, wv = threadIdx.x >> 6;
    if (!lane) rs[wv] = s;
    __syncthreads();
    if (threadIdx.x == 0) rtot = 1.0f / fmaxf(sqrtf(rs[0] + rs[1] + rs[2] + rs[3]), 1e-12f);
    __syncthreads();
    float rn = rtot;
    for (int u = threadIdx.x * 4; u < N_; u += 1024) {
        float4 v = *(const float4*)&row[u];
        v.x *= rn; v.y *= rn; v.z *= rn; v.w *= rn;
        *(float4*)&row[u] = v;
    }
}

// ---------------- cross-attn scores + softmax: A[b][h][d][e] = softmax_e( sum_n q[d][n] k[e][n] )
__global__ __launch_bounds__(256) void k_ca_score(const float* __restrict__ T, float* __restrict__ A) {
    int d = blockIdx.x, h = blockIdx.y, b = blockIdx.z;
    const float* q = T + ((size_t)b * 768 + h * 32 + d) * N_;
    const float* k = T + ((size_t)b * 768 + 256 + h * 32) * N_;
    float acc[32];
#pragma unroll
    for (int e = 0; e < 32; ++e) acc[e] = 0.f;
    for (int n = threadIdx.x; n < N_; n += 256) {
        float qv = q[n];
#pragma unroll
        for (int e = 0; e < 32; ++e) acc[e] += qv * k[(size_t)e * N_ + n];
    }
    __shared__ float red[4][32]; __shared__ float row[32];
    int lane = threadIdx.x & 63, wv = threadIdx.x >> 6;
#pragma unroll
    for (int e = 0; e < 32; ++e) {
        float v = acc[e];
#pragma unroll
        for (int off = 32; off; off >>= 1) v += __shfl_down(v, off);
        if (!lane) red[wv][e] = v;
    }
    __syncthreads();
    if (threadIdx.x < 32)
        row[threadIdx.x] = red[0][threadIdx.x] + red[1][threadIdx.x] + red[2][threadIdx.x] + red[3][threadIdx.x];
    __syncthreads();
    if (threadIdx.x < 32) {
        float v = row[threadIdx.x];
        float m = v;
#pragma unroll
        for (int off = 16; off; off >>= 1) m = fmaxf(m, __shfl_xor(m, off, 32));
        float ex = __expf(v - m);
        float ssum = ex;
#pragma unroll
        for (int off = 16; off; off >>= 1) ssum += __shfl_xor(ssum, off, 32);
        A[(((size_t)b * NH + h) * 32 + d) * 32 + threadIdx.x] = ex / ssum;
    }
}

// ---------------- apply: XCA[b][h*32+d][n] = sum_e A[b][h][d][e] * v[b][h][e][n]
__global__ __launch_bounds__(256) void k_ca_apply(const float* __restrict__ T, const float* __restrict__ A,
                                                  float* __restrict__ XCA) {
    int n0 = blockIdx.x * 256, h = blockIdx.y, b = blockIdx.z;
    __shared__ float Ae[32][32];  // [e][d] for vectorized d-reads
    const float* Ab = A + ((size_t)b * NH + h) * 1024;
    for (int u = threadIdx.x; u < 1024; u += 256) { int d = u >> 5, e = u & 31; Ae[e][d] = Ab[u]; }
    __syncthreads();
    int n = n0 + threadIdx.x;
    const float* V = T + ((size_t)b * 768 + 512 + h * 32) * N_ + n;
    float acc[32];
#pragma unroll
    for (int d = 0; d < 32; ++d) acc[d] = 0.f;
#pragma unroll
    for (int e = 0; e < 32; ++e) {
        float v = V[(size_t)e * N_];
#pragma unroll
        for (int dg = 0; dg < 8; ++dg) {
            float4 a4 = *(const float4*)&Ae[e][dg * 4];
            acc[dg * 4 + 0] += a4.x * v; acc[dg * 4 + 1] += a4.y * v;
            acc[dg * 4 + 2] += a4.z * v; acc[dg * 4 + 3] += a4.w * v;
        }
    }
    float* o = XCA + ((size_t)b * C_ + h * 32) * N_ + n;
#pragma unroll
    for (int d = 0; d < 32; ++d) o[(size_t)d * N_] = acc[d];
}

// ---------------- out2 gemm + residual: ATT[b][c][n] = x + gamma1[c]*(XCA^T @ W_out2 + b_out2)
__global__ __launch_bounds__(256) void k_out2_res(const float* __restrict__ W2, const float* __restrict__ bias2,
                                                  const float* __restrict__ g1, const float* __restrict__ X,
                                                  const float* __restrict__ XCA, float* __restrict__ ATT) {
    __shared__ float As[16][64], Bs[16][64];
    int n0 = blockIdx.x * 64, m0 = blockIdx.y * 64, b = blockIdx.z;
    int tid = threadIdx.x, tm = tid & 15, tn = tid >> 4;
    float acc[4][4] = {};
    const float* Xc = XCA + (size_t)b * C_ * N_;
    for (int c0 = 0; c0 < 256; c0 += 16) {
#pragma unroll
        for (int i = 0; i < 4; ++i) {
            int e = tid + 256 * i; int kk = e >> 6, m = e & 63;
            As[kk][m] = W2[(size_t)(c0 + kk) * 256 + m0 + m];
            Bs[kk][m] = Xc[(size_t)(c0 + kk) * N_ + n0 + m];
        }
        __syncthreads();
#pragma unroll
        for (int kk = 0; kk < 16; ++kk) {
            float4 a = *(const float4*)&As[kk][tm * 4];
            float4 bv = *(const float4*)&Bs[kk][tn * 4];
            float av[4] = {a.x, a.y, a.z, a.w}, bb[4] = {bv.x, bv.y, bv.z, bv.w};
#pragma unroll
            for (int i = 0; i < 4; ++i)
#pragma unroll
                for (int j = 0; j < 4; ++j) acc[i][j] += av[i] * bb[j];
        }
        __syncthreads();
    }
    const float* xin = X + (size_t)b * C_ * N_;
    float* Ao = ATT + (size_t)b * C_ * N_;
#pragma unroll
    for (int i = 0; i < 4; ++i) {
        int c = m0 + tm * 4 + i;
        float gv = g1[c], bi = bias2[c];
        float o[4];
#pragma unroll
        for (int j = 0; j < 4; ++j) {
            int n = n0 + tn * 4 + j;
            o[j] = xin[(size_t)c * N_ + n] + gv * (acc[i][j] + bi);
        }
        *(float4*)&Ao[(size_t)c * N_ + n0 + tn * 4] = make_float4(o[0], o[1], o[2], o[3]);
    }
}

// ---------------- conv 3x3x3 as implicit GEMM: Y[b][co][n] = sum_{t,ci} WT[t][ci][co]*ATT[b][ci][shift_t(n)]
__global__ __launch_bounds__(256) void k_conv(const float* __restrict__ WT, const float* __restrict__ ATT,
                                              float* __restrict__ Y) {
    __shared__ float As[16][64], Bs[16][64];
    int n0 = blockIdx.x * 64, co0 = blockIdx.y * 64, b = blockIdx.z;
    int tid = threadIdx.x, tm = tid & 15, tn = tid >> 4;
    float acc[4][4] = {};
    const float* Ab = ATT + (size_t)b * C_ * N_;
    for (int t = 0; t < 27; ++t) {
        int dz = t / 9 - 1, dy = (t / 3) % 3 - 1, dx = t % 3 - 1;
        for (int cc = 0; cc < 256; cc += 16) {
#pragma unroll
            for (int i = 0; i < 4; ++i) {
                int e = tid + 256 * i; int kk = e >> 6, m = e & 63;
                As[kk][m] = WT[((size_t)t * 256 + cc + kk) * 256 + co0 + m];  // coalesced in co
                int n = n0 + m;
                int z = (n >> 8) + dz, y = ((n >> 4) & 15) + dy, x = (n & 15) + dx;
                float v = 0.f;
                if ((unsigned)z < 16u && (unsigned)y < 16u && (unsigned)x < 16u)
                    v = Ab[(size_t)(cc + kk) * N_ + (z << 8) + (y << 4) + x];
                Bs[kk][m] = v;
            }
            __syncthreads();
#pragma unroll
            for (int kk = 0; kk < 16; ++kk) {
                float4 a = *(const float4*)&As[kk][tm * 4];
                float4 bv = *(const float4*)&Bs[kk][tn * 4];
                float av[4] = {a.x, a.y, a.z, a.w}, bb[4] = {bv.x, bv.y, bv.z, bv.w};
#pragma unroll
                for (int ii = 0; ii < 4; ++ii)
#pragma unroll
                    for (int jj = 0; jj < 4; ++jj) acc[ii][jj] += av[ii] * bb[jj];
            }
            __syncthreads();
        }
    }
    float* Yb = Y + ((size_t)b * C_ + co0) * N_ + n0;
#pragma unroll
    for (int i = 0; i < 4; ++i) {
        float4 st = make_float4(acc[i][0], acc[i][1], acc[i][2], acc[i][3]);
        *(float4*)&Yb[(size_t)(tm * 4 + i) * N_ + tn * 4] = st;
    }
}

// ---------------- per-batch mean/var partial sums
__global__ __launch_bounds__(256) void k_gn_reduce(const float* __restrict__ Y, float* __restrict__ RED) {
    int blk = blockIdx.x, b = blockIdx.y;
    const float* p = Y + (size_t)b * C_ * N_ + (size_t)blk * 16384;
    float s = 0.f, q = 0.f;
    for (int u = threadIdx.x * 4; u < 16384; u += 1024) {
        float4 v = *(const float4*)&p[u];
        s += v.x + v.y + v.z + v.w;
        q += v.x * v.x + v.y * v.y + v.z * v.z + v.w * v.w;
    }
#pragma unroll
    for (int off = 32; off; off >>= 1) { s += __shfl_down(s, off); q += __shfl_down(q, off); }
    __shared__ float rs[4], rq[4];
    int lane = threadIdx.x & 63, wv = threadIdx.x >> 6;
    if (!lane) { rs[wv] = s; rq[wv] = q; }
    __syncthreads();
    if (threadIdx.x == 0) {
        RED[((size_t)b * 64 + blk) * 2 + 0] = rs[0] + rs[1] + rs[2] + rs[3];
        RED[((size_t)b * 64 + blk) * 2 + 1] = rq[0] + rq[1] + rq[2] + rq[3];
    }
}

__global__ void k_gn_finalize(const float* __restrict__ RED, float* __restrict__ MU) {
    int b = blockIdx.x;
    float s = RED[((size_t)b * 64 + threadIdx.x) * 2 + 0];
    float q = RED[((size_t)b * 64 + threadIdx.x) * 2 + 1];
#pragma unroll
    for (int off = 32; off; off >>= 1) { s += __shfl_down(s, off); q += __shfl_down(q, off); }
    if (threadIdx.x == 0) {
        float inv = 1.0f / (float)(C_ * N_);
        float mu = s * inv, var = q * inv - mu * mu;
        MU[b * 2 + 0] = mu;
        MU[b * 2 + 1] = rsqrtf(var + 1e-5f);
    }
}

// ---------------- normalize + affine + residual + leaky relu -> fp32 out
__global__ __launch_bounds__(256) void k_final(const float* __restrict__ Y, const float* __restrict__ ATT,
                                               const float* __restrict__ MU, const float* __restrict__ gw,
                                               const float* __restrict__ gb, float* __restrict__ out) {
    int i = blockIdx.x * 256 + threadIdx.x;
    int b = i >> 20;            // 2^20 elems per batch
    int c = (i >> 12) & 255;    // 2^12 = N
    float mu = MU[b * 2], rstd = MU[b * 2 + 1];
    float v = (Y[i] - mu) * rstd * gw[c] + gb[c] + ATT[i];
    out[i] = v >= 0.f ? v : 0.01f * v;
}

extern "C" void kernel_launch(void* const* d_in, const int* in_sizes, int n_in,
                              void* d_out, int out_size, void* d_ws, size_t ws_size,
                              hipStream_t stream) {
    const float* x      = (const float*)d_in[0];
    const float* Wqkvv  = (const float*)d_in[1];
    // d_in[2] W_out, d_in[3] b_out, d_in[10] index_sample: DEAD in reference
    const float* W_out2 = (const float*)d_in[4];
    const float* b_out2 = (const float*)d_in[5];
    const float* gamma1 = (const float*)d_in[6];
    const float* conv_w = (const float*)d_in[7];
    const float* gn_w   = (const float*)d_in[8];
    const float* gn_b   = (const float*)d_in[9];
    float* out = (float*)d_out;
    float* ws = (float*)d_ws;

    float* T   = ws + OFF_T;
    float* Aca = ws + OFF_A;
    float* XCA = ws + OFF_XCA;
    float* ATT = ws + OFF_ATT;
    float* WT  = ws + OFF_WT;
    float* RED = ws + OFF_RED;
    float* MU  = ws + OFF_MU;
    float* Y   = ws + OFF_T;   // alias: qkv_t buffer is dead after k_ca_apply

    k_prep_w   <<<SZ_WT / 256, 256, 0, stream>>>(conv_w, WT);
    k_gemm_qkv <<<dim3(N_ / 64, 768 / 64, B_), 256, 0, stream>>>(Wqkvv, x, T);
    k_l2norm   <<<B_ * 512, 256, 0, stream>>>(T);
    k_ca_score <<<dim3(32, NH, B_), 256, 0, stream>>>(T, Aca);
    k_ca_apply <<<dim3(N_ / 256, NH, B_), 256, 0, stream>>>(T, Aca, XCA);
    k_out2_res <<<dim3(N_ / 64, C_ / 64, B_), 256, 0, stream>>>(W_out2, b_out2, gamma1, x, XCA, ATT);
    k_conv     <<<dim3(N_ / 64, C_ / 64, B_), 256, 0, stream>>>(WT, ATT, Y);
    k_gn_reduce<<<dim3(64, B_), 256, 0, stream>>>(Y, RED);
    k_gn_finalize<<<B_, 64, 0, stream>>>(RED, MU);
    k_final    <<<(B_ * C_ * N_) / 256, 256, 0, stream>>>(Y, ATT, MU, gn_w, gn_b, out);
}

// Round 3
// 248.407 us; speedup vs baseline: 3.7893x; 3.7893x over previous
//
#include <hip/hip_runtime.h>
#include <hip/hip_bf16.h>
#include <stdint.h>

// Problem: B=2, C=256, H=W=D=16 -> N=4096, nh=8, dh=32. ALL float32 I/O.
// Reference dead code: x_sa path (top-k, index_sample, W_out, b_out, v_sa) — epa = x_ca only.
// This round: conv (29 GFLOP) + qkv (3.2 GFLOP) moved to bf16 MFMA 16x16x32,
// m97-style 128x128 tiles with global_load_lds width-16 staging.

#define B_ 2
#define C_ 256
#define N_ 4096
#define NH 8
#define PADV 5832   // 18*18*18 zero-padded spatial volume for conv halo

typedef unsigned short u16;
typedef unsigned int   u32;

using frag16 = __attribute__((ext_vector_type(8))) short;   // 8 bf16 = 4 VGPR
using f32x4  = __attribute__((ext_vector_type(4))) float;   // MFMA C/D

__device__ __forceinline__ u16 f2bf(float f) {              // RNE float->bf16 bits
    u32 u = __float_as_uint(f);
    u += 0x7fff + ((u >> 16) & 1);
    return (u16)(u >> 16);
}
__device__ __forceinline__ void gld16(const void* g, void* l) {
    __builtin_amdgcn_global_load_lds((const __attribute__((address_space(1))) u32*)g,
                                     (__attribute__((address_space(3))) u32*)l, 16, 0, 0);
}
__device__ __forceinline__ int padrow(int n) {  // flat n -> padded 18^3 row index (center tap)
    int z = n >> 8, y = (n >> 4) & 15, x = n & 15;
    return (z + 1) * 324 + (y + 1) * 18 + (x + 1);
}

// ---- workspace layout (float units). Round-2 used 49MB OK; this is 47.7MB.
#define OFF_T    0                         // [B][768][N] fp32 qkv rows (q:0-255,k:256-511,v:512-767)
#define SZ_T     (B_*768*N_)               // 6291456
#define OFF_PK   0                         // alias over T: conv partials [2][B][C][N] fp32 = 4194304
#define OFF_ATT  4194304                   // alias inside T tail: attn fp32 [B][C][N] = 2097152
#define OFF_A    (OFF_T + SZ_T)            // attn_ca [B][NH][32][32]
#define OFF_XCA  (OFF_A + 2048)            // [B][C][N] fp32 (later aliased as Y)
#define OFF_ATTP (OFF_XCA + B_*C_*N_)      // bf16 padded attn [B][PADV][C] = 1492992 floats
#define OFF_WT2  (OFF_ATTP + (B_*PADV*C_)/2)   // bf16 [27][co][ci] = 884736 floats
#define OFF_WQB  (OFF_WT2 + (27*C_*C_)/2)      // bf16 [768][256]   = 98304 floats
#define OFF_XT   (OFF_WQB + (768*C_)/2)        // bf16 [B][N][C]    = 1048576 floats
#define OFF_RED  (OFF_XT + (B_*N_*C_)/2)
#define OFF_MU   (OFF_RED + B_*64*2)

// ================ prep kernels ================
__global__ __launch_bounds__(256) void k_prep_w2(const float* __restrict__ CW, u16* __restrict__ WT2) {
    int o = blockIdx.x * 256 + threadIdx.x;          // 27*256*256
    int ci = o & 255, co = (o >> 8) & 255, t = o >> 16;
    WT2[o] = f2bf(CW[((size_t)co * 256 + ci) * 27 + t]);
}
__global__ __launch_bounds__(256) void k_prep_wq(const float* __restrict__ Wq, u16* __restrict__ Wqb) {
    int o = blockIdx.x * 256 + threadIdx.x;          // 768*256
    int c = o & 255, j = o >> 8;
    Wqb[o] = f2bf(Wq[(size_t)c * 1024 + j]);
}
__global__ __launch_bounds__(256) void k_prep_x(const float* __restrict__ X, u16* __restrict__ XT) {
    __shared__ float ts[32][33];
    int n0 = blockIdx.x * 32, c0 = blockIdx.y * 32, b = blockIdx.z;
    int tx = threadIdx.x & 31, ty = threadIdx.x >> 5;   // 32x8
    const float* Xb = X + (size_t)b * C_ * N_;
#pragma unroll
    for (int i = 0; i < 4; ++i) ts[ty + i * 8][tx] = Xb[(size_t)(c0 + ty + i * 8) * N_ + n0 + tx];
    __syncthreads();
    u16* Xo = XT + (size_t)b * N_ * C_;
#pragma unroll
    for (int i = 0; i < 4; ++i) Xo[(size_t)(n0 + ty + i * 8) * C_ + c0 + tx] = f2bf(ts[tx][ty + i * 8]);
}
__global__ __launch_bounds__(256) void k_zero_pad(u32* __restrict__ p) {
    int i = blockIdx.x * 256 + threadIdx.x;          // B*PADV*C/2 u32 = 1492992
    p[i] = 0;
}

// ================ QKV MFMA gemm: T[b][j][n] = sum_c Wqb[j][c] * XT[b][n][c] ================
__global__ __launch_bounds__(256) void k_qkv_mfma(const u16* __restrict__ Wqb, const u16* __restrict__ XT,
                                                  float* __restrict__ T) {
    __shared__ __align__(16) u16 As[128 * 32], Bs[128 * 32];   // [row][k], rows of 64B
    int n0 = blockIdx.x * 128, j0 = blockIdx.y * 128, b = blockIdx.z;
    int tid = threadIdx.x, lane = tid & 63, w = tid >> 6;
    int wm = w & 1, wn = w >> 1, qm = lane >> 4, lm = lane & 15;
    int rs = lane >> 2, cs = (lane & 3) * 8;
    f32x4 acc[4][4] = {};
    const u16* Ab = Wqb + (size_t)(j0 + w * 32 + rs) * 256 + cs;
    const u16* Bb = XT + (size_t)b * N_ * C_ + (size_t)(n0 + w * 32 + rs) * 256 + cs;
#pragma unroll
    for (int kc = 0; kc < 8; ++kc) {
        gld16(Ab + kc * 32,            As + w * 1024);
        gld16(Ab + 16 * 256 + kc * 32, As + w * 1024 + 512);
        gld16(Bb + kc * 32,            Bs + w * 1024);
        gld16(Bb + 16 * 256 + kc * 32, Bs + w * 1024 + 512);
        __syncthreads();
        frag16 af[4], bf[4];
#pragma unroll
        for (int i = 0; i < 4; ++i) af[i] = *(const frag16*)&As[(wm * 64 + i * 16 + lm) * 32 + qm * 8];
#pragma unroll
        for (int j = 0; j < 4; ++j) bf[j] = *(const frag16*)&Bs[(wn * 64 + j * 16 + lm) * 32 + qm * 8];
#pragma unroll
        for (int i = 0; i < 4; ++i)
#pragma unroll
            for (int j = 0; j < 4; ++j)
                acc[i][j] = __builtin_amdgcn_mfma_f32_16x16x32_bf16(af[i], bf[j], acc[i][j], 0, 0, 0);
        __syncthreads();
    }
    float* Tb = T + ((size_t)b * 768 + j0 + wm * 64) * N_ + n0 + wn * 64;
#pragma unroll
    for (int i = 0; i < 4; ++i)
#pragma unroll
        for (int j = 0; j < 4; ++j)
#pragma unroll
            for (int r = 0; r < 4; ++r)
                Tb[(size_t)(i * 16 + qm * 4 + r) * N_ + j * 16 + lm] = acc[i][j][r];
}

// ================ l2norm over n for q,k rows (j<512) ================
__global__ __launch_bounds__(256) void k_l2norm(float* __restrict__ T) {
    int bj = blockIdx.x; int b = bj >> 9, j = bj & 511;
    float* row = T + ((size_t)b * 768 + j) * N_;
    float s = 0.f;
    for (int u = threadIdx.x * 4; u < N_; u += 1024) {
        float4 v = *(const float4*)&row[u];
        s += v.x * v.x + v.y * v.y + v.z * v.z + v.w * v.w;
    }
#pragma unroll
    for (int off = 32; off; off >>= 1) s += __shfl_down(s, off);
    __shared__ float rs[4]; __shared__ float rtot;
    int lane = threadIdx.x & 63, wv = threadIdx.x >> 6;
    if (!lane) rs[wv] = s;
    __syncthreads();
    if (threadIdx.x == 0) rtot = 1.0f / fmaxf(sqrtf(rs[0] + rs[1] + rs[2] + rs[3]), 1e-12f);
    __syncthreads();
    float rn = rtot;
    for (int u = threadIdx.x * 4; u < N_; u += 1024) {
        float4 v = *(const float4*)&row[u];
        v.x *= rn; v.y *= rn; v.z *= rn; v.w *= rn;
        *(float4*)&row[u] = v;
    }
}

// ================ cross-attn scores+softmax (unchanged; 41ms rocprof row was an artifact) ==========
__global__ __launch_bounds__(256) void k_ca_score(const float* __restrict__ T, float* __restrict__ A) {
    int d = blockIdx.x, h = blockIdx.y, b = blockIdx.z;
    const float* q = T + ((size_t)b * 768 + h * 32 + d) * N_;
    const float* k = T + ((size_t)b * 768 + 256 + h * 32) * N_;
    float acc[32];
#pragma unroll
    for (int e = 0; e < 32; ++e) acc[e] = 0.f;
    for (int n = threadIdx.x; n < N_; n += 256) {
        float qv = q[n];
#pragma unroll
        for (int e = 0; e < 32; ++e) acc[e] += qv * k[(size_t)e * N_ + n];
    }
    __shared__ float red[4][32]; __shared__ float row[32];
    int lane = threadIdx.x & 63, wv = threadIdx.x >> 6;
#pragma unroll
    for (int e = 0; e < 32; ++e) {
        float v = acc[e];
#pragma unroll
        for (int off = 32; off; off >>= 1) v += __shfl_down(v, off);
        if (!lane) red[wv][e] = v;
    }
    __syncthreads();
    if (threadIdx.x < 32)
        row[threadIdx.x] = red[0][threadIdx.x] + red[1][threadIdx.x] + red[2][threadIdx.x] + red[3][threadIdx.x];
    __syncthreads();
    if (threadIdx.x < 32) {
        float v = row[threadIdx.x];
        float m = v;
#pragma unroll
        for (int off = 16; off; off >>= 1) m = fmaxf(m, __shfl_xor(m, off, 32));
        float ex = __expf(v - m);
        float ssum = ex;
#pragma unroll
        for (int off = 16; off; off >>= 1) ssum += __shfl_xor(ssum, off, 32);
        A[(((size_t)b * NH + h) * 32 + d) * 32 + threadIdx.x] = ex / ssum;
    }
}

// ================ apply: XCA[b][h*32+d][n] = sum_e A[d][e] v[e][n] ================
__global__ __launch_bounds__(256) void k_ca_apply(const float* __restrict__ T, const float* __restrict__ A,
                                                  float* __restrict__ XCA) {
    int n0 = blockIdx.x * 256, h = blockIdx.y, b = blockIdx.z;
    __shared__ float Ae[32][32];
    const float* Ab = A + ((size_t)b * NH + h) * 1024;
    for (int u = threadIdx.x; u < 1024; u += 256) { int d = u >> 5, e = u & 31; Ae[e][d] = Ab[u]; }
    __syncthreads();
    int n = n0 + threadIdx.x;
    const float* V = T + ((size_t)b * 768 + 512 + h * 32) * N_ + n;
    float acc[32];
#pragma unroll
    for (int d = 0; d < 32; ++d) acc[d] = 0.f;
#pragma unroll
    for (int e = 0; e < 32; ++e) {
        float v = V[(size_t)e * N_];
#pragma unroll
        for (int dg = 0; dg < 8; ++dg) {
            float4 a4 = *(const float4*)&Ae[e][dg * 4];
            acc[dg * 4 + 0] += a4.x * v; acc[dg * 4 + 1] += a4.y * v;
            acc[dg * 4 + 2] += a4.z * v; acc[dg * 4 + 3] += a4.w * v;
        }
    }
    float* o = XCA + ((size_t)b * C_ + h * 32) * N_ + n;
#pragma unroll
    for (int d = 0; d < 32; ++d) o[(size_t)d * N_] = acc[d];
}

// ================ out2 gemm + residual; writes fp32 ATT + bf16 padded ATTp ================
__global__ __launch_bounds__(256) void k_out2_res(const float* __restrict__ W2, const float* __restrict__ bias2,
                                                  const float* __restrict__ g1, const float* __restrict__ X,
                                                  const float* __restrict__ XCA, float* __restrict__ ATT,
                                                  u16* __restrict__ ATTp) {
    __shared__ float As[16][64], Bs[16][64];
    int n0 = blockIdx.x * 64, m0 = blockIdx.y * 64, b = blockIdx.z;
    int tid = threadIdx.x, tm = tid & 15, tn = tid >> 4;
    float acc[4][4] = {};
    const float* Xc = XCA + (size_t)b * C_ * N_;
    for (int c0 = 0; c0 < 256; c0 += 16) {
#pragma unroll
        for (int i = 0; i < 4; ++i) {
            int e = tid + 256 * i; int kk = e >> 6, m = e & 63;
            As[kk][m] = W2[(size_t)(c0 + kk) * 256 + m0 + m];
            Bs[kk][m] = Xc[(size_t)(c0 + kk) * N_ + n0 + m];
        }
        __syncthreads();
#pragma unroll
        for (int kk = 0; kk < 16; ++kk) {
            float4 a = *(const float4*)&As[kk][tm * 4];
            float4 bv = *(const float4*)&Bs[kk][tn * 4];
            float av[4] = {a.x, a.y, a.z, a.w}, bb[4] = {bv.x, bv.y, bv.z, bv.w};
#pragma unroll
            for (int i = 0; i < 4; ++i)
#pragma unroll
                for (int j = 0; j < 4; ++j) acc[i][j] += av[i] * bb[j];
        }
        __syncthreads();
    }
    const float* xin = X + (size_t)b * C_ * N_;
    float val[4][4];
#pragma unroll
    for (int i = 0; i < 4; ++i) {
        int c = m0 + tm * 4 + i;
        float gv = g1[c], bi = bias2[c];
#pragma unroll
        for (int j = 0; j < 4; ++j)
            val[i][j] = xin[(size_t)c * N_ + n0 + tn * 4 + j] + gv * (acc[i][j] + bi);
    }
    float* Ao = ATT + (size_t)b * C_ * N_;
#pragma unroll
    for (int i = 0; i < 4; ++i)
        *(float4*)&Ao[(size_t)(m0 + tm * 4 + i) * N_ + n0 + tn * 4] =
            make_float4(val[i][0], val[i][1], val[i][2], val[i][3]);
    u16* Ap = ATTp + (size_t)b * PADV * C_;
#pragma unroll
    for (int j = 0; j < 4; ++j) {
        int n = n0 + tn * 4 + j;
        int pr = padrow(n);
        ushort4 pk;
        pk.x = f2bf(val[0][j]); pk.y = f2bf(val[1][j]);
        pk.z = f2bf(val[2][j]); pk.w = f2bf(val[3][j]);
        *(ushort4*)&Ap[(size_t)pr * 256 + m0 + tm * 4] = pk;
    }
}

// ================ conv 3^3 MFMA implicit GEMM, split-K=2 over taps ================
// Pk[ks][b][co][n] = sum_{t in half, ci} WT2[t][co][ci] * ATTp[b][padrow(n)+toff(t)][ci]
__global__ __launch_bounds__(256) void k_conv_mfma(const u16* __restrict__ WT2, const u16* __restrict__ ATTp,
                                                   float* __restrict__ Pk) {
    __shared__ __align__(16) u16 As[128 * 32], Bs[128 * 32];
    int n0 = blockIdx.x * 128, co0 = blockIdx.y * 128;
    int b = blockIdx.z >> 1, ks = blockIdx.z & 1;
    int t0 = ks ? 14 : 0, t1 = ks ? 27 : 14;
    int tid = threadIdx.x, lane = tid & 63, w = tid >> 6;
    int wm = w & 1, wn = w >> 1, qm = lane >> 4, lm = lane & 15;
    int rs = lane >> 2, cs = (lane & 3) * 8;
    int pr0 = padrow(n0 + w * 32 + rs);
    int pr1 = padrow(n0 + w * 32 + 16 + rs);
    const u16* Apb = ATTp + (size_t)b * PADV * C_;
    f32x4 acc[4][4] = {};
    for (int t = t0; t < t1; ++t) {
        int dz = t / 9 - 1, dy = (t / 3) % 3 - 1, dx = t % 3 - 1;
        int toff = dz * 324 + dy * 18 + dx;
        const u16* Ab  = WT2 + ((size_t)t * 256 + co0 + w * 32 + rs) * 256 + cs;
        const u16* Bb0 = Apb + (size_t)(pr0 + toff) * 256 + cs;
        const u16* Bb1 = Apb + (size_t)(pr1 + toff) * 256 + cs;
#pragma unroll
        for (int kc = 0; kc < 8; ++kc) {
            gld16(Ab + kc * 32,            As + w * 1024);
            gld16(Ab + 16 * 256 + kc * 32, As + w * 1024 + 512);
            gld16(Bb0 + kc * 32,           Bs + w * 1024);
            gld16(Bb1 + kc * 32,           Bs + w * 1024 + 512);
            __syncthreads();
            frag16 af[4], bf[4];
#pragma unroll
            for (int i = 0; i < 4; ++i) af[i] = *(const frag16*)&As[(wm * 64 + i * 16 + lm) * 32 + qm * 8];
#pragma unroll
            for (int j = 0; j < 4; ++j) bf[j] = *(const frag16*)&Bs[(wn * 64 + j * 16 + lm) * 32 + qm * 8];
#pragma unroll
            for (int i = 0; i < 4; ++i)
#pragma unroll
                for (int j = 0; j < 4; ++j)
                    acc[i][j] = __builtin_amdgcn_mfma_f32_16x16x32_bf16(af[i], bf[j], acc[i][j], 0, 0, 0);
            __syncthreads();
        }
    }
    float* Pb = Pk + ((size_t)(ks * B_ + b) * C_ + co0 + wm * 64) * N_ + n0 + wn * 64;
#pragma unroll
    for (int i = 0; i < 4; ++i)
#pragma unroll
        for (int j = 0; j < 4; ++j)
#pragma unroll
            for (int r = 0; r < 4; ++r)
                Pb[(size_t)(i * 16 + qm * 4 + r) * N_ + j * 16 + lm] = acc[i][j][r];
}

// ================ combine split-K partials + batch mean/var partial sums ================
__global__ __launch_bounds__(256) void k_gn_reduce(const float* __restrict__ Pk, float* __restrict__ Y,
                                                   float* __restrict__ RED) {
    int blk = blockIdx.x, b = blockIdx.y;
    size_t off = (size_t)b * C_ * N_ + (size_t)blk * 16384;
    const float* p0 = Pk + off;
    const float* p1 = Pk + (size_t)B_ * C_ * N_ + off;
    float* y = Y + off;
    float s = 0.f, q = 0.f;
    for (int u = threadIdx.x * 4; u < 16384; u += 1024) {
        float4 a = *(const float4*)&p0[u];
        float4 c = *(const float4*)&p1[u];
        a.x += c.x; a.y += c.y; a.z += c.z; a.w += c.w;
        *(float4*)&y[u] = a;
        s += a.x + a.y + a.z + a.w;
        q += a.x * a.x + a.y * a.y + a.z * a.z + a.w * a.w;
    }
#pragma unroll
    for (int off2 = 32; off2; off2 >>= 1) { s += __shfl_down(s, off2); q += __shfl_down(q, off2); }
    __shared__ float rs[4], rq[4];
    int lane = threadIdx.x & 63, wv = threadIdx.x >> 6;
    if (!lane) { rs[wv] = s; rq[wv] = q; }
    __syncthreads();
    if (threadIdx.x == 0) {
        RED[((size_t)b * 64 + blk) * 2 + 0] = rs[0] + rs[1] + rs[2] + rs[3];
        RED[((size_t)b * 64 + blk) * 2 + 1] = rq[0] + rq[1] + rq[2] + rq[3];
    }
}

__global__ void k_gn_finalize(const float* __restrict__ RED, float* __restrict__ MU) {
    int b = blockIdx.x;
    float s = RED[((size_t)b * 64 + threadIdx.x) * 2 + 0];
    float q = RED[((size_t)b * 64 + threadIdx.x) * 2 + 1];
#pragma unroll
    for (int off = 32; off; off >>= 1) { s += __shfl_down(s, off); q += __shfl_down(q, off); }
    if (threadIdx.x == 0) {
        float inv = 1.0f / (float)(C_ * N_);
        float mu = s * inv, var = q * inv - mu * mu;
        MU[b * 2 + 0] = mu;
        MU[b * 2 + 1] = rsqrtf(var + 1e-5f);
    }
}

// ================ normalize + affine + residual + leaky relu ================
__global__ __launch_bounds__(256) void k_final(const float* __restrict__ Y, const float* __restrict__ ATT,
                                               const float* __restrict__ MU, const float* __restrict__ gw,
                                               const float* __restrict__ gb, float* __restrict__ out) {
    int i = blockIdx.x * 256 + threadIdx.x;
    int b = i >> 20;
    int c = (i >> 12) & 255;
    float mu = MU[b * 2], rstd = MU[b * 2 + 1];
    float v = (Y[i] - mu) * rstd * gw[c] + gb[c] + ATT[i];
    out[i] = v >= 0.f ? v : 0.01f * v;
}

extern "C" void kernel_launch(void* const* d_in, const int* in_sizes, int n_in,
                              void* d_out, int out_size, void* d_ws, size_t ws_size,
                              hipStream_t stream) {
    const float* x      = (const float*)d_in[0];
    const float* Wqkvv  = (const float*)d_in[1];
    // d_in[2] W_out, d_in[3] b_out, d_in[10] index_sample: DEAD in reference
    const float* W_out2 = (const float*)d_in[4];
    const float* b_out2 = (const float*)d_in[5];
    const float* gamma1 = (const float*)d_in[6];
    const float* conv_w = (const float*)d_in[7];
    const float* gn_w   = (const float*)d_in[8];
    const float* gn_b   = (const float*)d_in[9];
    float* out = (float*)d_out;
    float* ws = (float*)d_ws;

    float* T    = ws + OFF_T;
    float* Pk   = ws + OFF_PK;     // alias over T (T dead after ca_apply)
    float* ATT  = ws + OFF_ATT;    // alias inside T tail
    float* Aca  = ws + OFF_A;
    float* XCA  = ws + OFF_XCA;
    float* Y    = ws + OFF_XCA;    // alias (XCA dead after out2_res)
    u16*   ATTp = (u16*)(ws + OFF_ATTP);
    u16*   WT2  = (u16*)(ws + OFF_WT2);
    u16*   Wqb  = (u16*)(ws + OFF_WQB);
    u16*   XT   = (u16*)(ws + OFF_XT);
    float* RED  = ws + OFF_RED;
    float* MU   = ws + OFF_MU;

    k_prep_w2  <<<27 * 256, 256, 0, stream>>>(conv_w, WT2);
    k_prep_wq  <<<768, 256, 0, stream>>>(Wqkvv, Wqb);
    k_prep_x   <<<dim3(N_ / 32, C_ / 32, B_), 256, 0, stream>>>(x, XT);
    k_zero_pad <<<(B_ * PADV * C_ / 2) / 256, 256, 0, stream>>>((u32*)ATTp);
    k_qkv_mfma <<<dim3(N_ / 128, 768 / 128, B_), 256, 0, stream>>>(Wqb, XT, T);
    k_l2norm   <<<B_ * 512, 256, 0, stream>>>(T);
    k_ca_score <<<dim3(32, NH, B_), 256, 0, stream>>>(T, Aca);
    k_ca_apply <<<dim3(N_ / 256, NH, B_), 256, 0, stream>>>(T, Aca, XCA);
    k_out2_res <<<dim3(N_ / 64, C_ / 64, B_), 256, 0, stream>>>(W_out2, b_out2, gamma1, x, XCA, ATT, ATTp);
    k_conv_mfma<<<dim3(N_ / 128, C_ / 128, B_ * 2), 256, 0, stream>>>(WT2, ATTp, Pk);
    k_gn_reduce<<<dim3(64, B_), 256, 0, stream>>>(Pk, Y, RED);
    k_gn_finalize<<<B_, 64, 0, stream>>>(RED, MU);
    k_final    <<<(B_ * C_ * N_) / 256, 256, 0, stream>>>(Y, ATT, MU, gn_w, gn_b, out);
}

// Round 4
// 235.340 us; speedup vs baseline: 3.9997x; 1.0555x over previous
//
#include <hip/hip_runtime.h>
#include <hip/hip_bf16.h>
#include <stdint.h>

// B=2, C=256, H=W=D=16 -> N=4096, nh=8, dh=32. ALL float32 I/O.
// Reference dead code: x_sa path (top-k, index_sample, W_out, b_out, v_sa) — epa = x_ca only.
// Round 4: conv split-K=3 + LDS double-buffer + XOR bank swizzle; out2 -> MFMA;
// ca_score -> split-N partials; T stored bf16.

#define B_ 2
#define C_ 256
#define N_ 4096
#define NH 8
#define PADV 5832                    // 18^3 zero-padded spatial volume
#define CN  (C_*N_)                  // 1048576 = 2^20
#define BCN (B_*CN)                  // 2097152

typedef unsigned short u16;
typedef unsigned int   u32;

using frag16 = __attribute__((ext_vector_type(8))) short;   // 8 bf16 = 4 VGPR
using f32x4  = __attribute__((ext_vector_type(4))) float;   // MFMA C/D

__device__ __forceinline__ u16 f2bf(float f) {              // RNE float->bf16 bits
    u32 u = __float_as_uint(f);
    u += 0x7fff + ((u >> 16) & 1);
    return (u16)(u >> 16);
}
__device__ __forceinline__ float bb(u16 h) { return __uint_as_float((u32)h << 16); }
__device__ __forceinline__ void gld16(const void* g, void* l) {
    __builtin_amdgcn_global_load_lds((const __attribute__((address_space(1))) u32*)g,
                                     (__attribute__((address_space(3))) u32*)l, 16, 0, 0);
}
__device__ __forceinline__ int padrow(int n) {  // flat n -> padded 18^3 row (center tap)
    int z = n >> 8, y = (n >> 4) & 15, x = n & 15;
    return (z + 1) * 324 + (y + 1) * 18 + (x + 1);
}

// ---- workspace (float units), total ~48.3 MB (<= 49.0 MB proven in round 2)
#define OFF_TB    0            // bf16 T [B][768][N] (dead after ca_apply; window aliased by Pk)
#define OFF_ACA   3145728      // fp32 [B][NH][32][32] (dead after ca_apply)
#define OFF_XCAB  3147776      // bf16 [B][N][C] (dead after out2)
#define OFF_PK    0            // fp32 [3][B][C][N] = 6,291,456 fl — aliases the three above
#define OFF_ATT   6291456      // fp32 [B][C][N]
#define OFF_ATTP  8388608      // bf16 [B][PADV][C]
#define OFF_WT2   9881600      // bf16 [27][co][ci]
#define OFF_W2B   10766336     // bf16 [c][c'] (W_out2 transposed)
#define OFF_WQB   10799104     // bf16 [j][c]
#define OFF_XT    10897408     // bf16 [B][N][C]
#define OFF_SP    11945984     // fp32 [B][NH][8][1024] ca partials
#define OFF_RED   12077056
#define OFF_MU    12077312

// ================ prep kernels ================
__global__ __launch_bounds__(256) void k_prep_w2(const float* __restrict__ CW, u16* __restrict__ WT2) {
    int o = blockIdx.x * 256 + threadIdx.x;          // 27*256*256
    int ci = o & 255, co = (o >> 8) & 255, t = o >> 16;
    WT2[o] = f2bf(CW[((size_t)co * 256 + ci) * 27 + t]);
}
__global__ __launch_bounds__(256) void k_prep_w2b(const float* __restrict__ W2, u16* __restrict__ W2B) {
    __shared__ float ts[32][33];
    int c0 = blockIdx.x * 32, p0 = blockIdx.y * 32;   // c = out col of W2, p = in row
    int tx = threadIdx.x & 31, ty = threadIdx.x >> 5;
#pragma unroll
    for (int i = 0; i < 4; ++i) ts[ty + i * 8][tx] = W2[(size_t)(p0 + ty + i * 8) * 256 + c0 + tx];
    __syncthreads();
#pragma unroll
    for (int i = 0; i < 4; ++i) W2B[(size_t)(c0 + ty + i * 8) * 256 + p0 + tx] = f2bf(ts[tx][ty + i * 8]);
}
__global__ __launch_bounds__(256) void k_prep_wq(const float* __restrict__ Wq, u16* __restrict__ Wqb) {
    int o = blockIdx.x * 256 + threadIdx.x;          // 768*256
    int c = o & 255, j = o >> 8;
    Wqb[o] = f2bf(Wq[(size_t)c * 1024 + j]);
}
__global__ __launch_bounds__(256) void k_prep_x(const float* __restrict__ X, u16* __restrict__ XT) {
    __shared__ float ts[32][33];
    int n0 = blockIdx.x * 32, c0 = blockIdx.y * 32, b = blockIdx.z;
    int tx = threadIdx.x & 31, ty = threadIdx.x >> 5;
    const float* Xb = X + (size_t)b * CN;
#pragma unroll
    for (int i = 0; i < 4; ++i) ts[ty + i * 8][tx] = Xb[(size_t)(c0 + ty + i * 8) * N_ + n0 + tx];
    __syncthreads();
    u16* Xo = XT + (size_t)b * N_ * C_;
#pragma unroll
    for (int i = 0; i < 4; ++i) Xo[(size_t)(n0 + ty + i * 8) * C_ + c0 + tx] = f2bf(ts[tx][ty + i * 8]);
}
__global__ __launch_bounds__(256) void k_zero_pad(u32* __restrict__ p) {
    p[blockIdx.x * 256 + threadIdx.x] = 0;           // B*PADV*C/2 = 1,492,992 u32
}

// ================ QKV MFMA: Tb[b][j][n] = sum_c Wqb[j][c]*XT[b][n][c]  (bf16 out) ================
__global__ __launch_bounds__(256) void k_qkv_mfma(const u16* __restrict__ Wqb, const u16* __restrict__ XT,
                                                  u16* __restrict__ Tb) {
    __shared__ __align__(16) u16 As[2][4096], Bs[2][4096];
    int n0 = blockIdx.x * 128, j0 = blockIdx.y * 128, b = blockIdx.z;
    int tid = threadIdx.x, lane = tid & 63, w = tid >> 6;
    int wm = w & 1, wn = w >> 1, qm = lane >> 4, lm = lane & 15;
    int rs = lane >> 2;
    int swz = (((lane & 3) ^ ((rs >> 1) & 3)) << 3);          // staging XOR swizzle (u16 units)
    int rd  = ((qm ^ ((lm >> 1) & 3)) << 3);                  // read-side slot
    const u16* Ab = Wqb + (size_t)(j0 + w * 32 + rs) * 256 + swz;
    const u16* Bb = XT + ((size_t)b * N_ + n0 + w * 32 + rs) * 256 + swz;
    f32x4 acc[4][4] = {};
    auto stage = [&](int kc, int p) {
        gld16(Ab + kc * 32,            As[p] + w * 1024);
        gld16(Ab + 16 * 256 + kc * 32, As[p] + w * 1024 + 512);
        gld16(Bb + kc * 32,            Bs[p] + w * 1024);
        gld16(Bb + 16 * 256 + kc * 32, Bs[p] + w * 1024 + 512);
    };
    stage(0, 0);
    for (int kc = 0; kc < 8; ++kc) {
        int p = kc & 1;
        __syncthreads();
        if (kc + 1 < 8) stage(kc + 1, p ^ 1);
        frag16 af[4], bf[4];
#pragma unroll
        for (int i = 0; i < 4; ++i) af[i] = *(const frag16*)&As[p][(wm * 64 + i * 16 + lm) * 32 + rd];
#pragma unroll
        for (int j = 0; j < 4; ++j) bf[j] = *(const frag16*)&Bs[p][(wn * 64 + j * 16 + lm) * 32 + rd];
#pragma unroll
        for (int i = 0; i < 4; ++i)
#pragma unroll
            for (int j = 0; j < 4; ++j)
                acc[i][j] = __builtin_amdgcn_mfma_f32_16x16x32_bf16(af[i], bf[j], acc[i][j], 0, 0, 0);
    }
    u16* To = Tb + ((size_t)b * 768 + j0 + wm * 64) * N_ + n0 + wn * 64;
#pragma unroll
    for (int i = 0; i < 4; ++i)
#pragma unroll
        for (int j = 0; j < 4; ++j)
#pragma unroll
            for (int r = 0; r < 4; ++r)
                To[(size_t)(i * 16 + qm * 4 + r) * N_ + j * 16 + lm] = f2bf(acc[i][j][r]);
}

// ================ l2norm over n for q,k rows (bf16 in/out) ================
__global__ __launch_bounds__(256) void k_l2norm(u16* __restrict__ Tb) {
    int bj = blockIdx.x; int b = bj >> 9, j = bj & 511;
    u16* row = Tb + ((size_t)b * 768 + j) * N_;
    float s = 0.f;
    for (int u = threadIdx.x * 8; u < N_; u += 2048) {
        uint4 vv = *(const uint4*)(row + u);
        const u16* h = (const u16*)&vv;
#pragma unroll
        for (int i = 0; i < 8; ++i) { float f = bb(h[i]); s += f * f; }
    }
#pragma unroll
    for (int off = 32; off; off >>= 1) s += __shfl_down(s, off);
    __shared__ float rs_[4]; __shared__ float rtot;
    int lane = threadIdx.x & 63, wv = threadIdx.x >> 6;
    if (!lane) rs_[wv] = s;
    __syncthreads();
    if (threadIdx.x == 0) rtot = 1.0f / fmaxf(sqrtf(rs_[0] + rs_[1] + rs_[2] + rs_[3]), 1e-12f);
    __syncthreads();
    float rn = rtot;
    for (int u = threadIdx.x * 8; u < N_; u += 2048) {
        uint4 vv = *(const uint4*)(row + u);
        u16* h = (u16*)&vv;
#pragma unroll
        for (int i = 0; i < 8; ++i) h[i] = f2bf(bb(h[i]) * rn);
        *(uint4*)(row + u) = vv;
    }
}

// ================ ca scores, split over n-slices: SP[b][h][s][d*32+e] ================
__global__ __launch_bounds__(256) void k_ca_part(const u16* __restrict__ Tb, float* __restrict__ SP) {
    int s = blockIdx.x, h = blockIdx.y, b = blockIdx.z;
    int t = threadIdx.x, d = t & 31, eg = t >> 5;
    const u16* Q  = Tb + ((size_t)b * 768 + h * 32 + d) * N_ + s * 512;
    const u16* K0 = Tb + ((size_t)b * 768 + 256 + h * 32 + eg * 4) * N_ + s * 512;
    float a0 = 0.f, a1 = 0.f, a2 = 0.f, a3 = 0.f;
    for (int u = 0; u < 512; u += 8) {
        uint4 qv = *(const uint4*)(Q + u);
        uint4 k0 = *(const uint4*)(K0 + u);
        uint4 k1 = *(const uint4*)(K0 + (size_t)N_ + u);
        uint4 k2 = *(const uint4*)(K0 + (size_t)2 * N_ + u);
        uint4 k3 = *(const uint4*)(K0 + (size_t)3 * N_ + u);
        const u16 *qh = (const u16*)&qv, *h0 = (const u16*)&k0, *h1 = (const u16*)&k1,
                  *h2 = (const u16*)&k2, *h3 = (const u16*)&k3;
#pragma unroll
        for (int i = 0; i < 8; ++i) {
            float qf = bb(qh[i]);
            a0 += qf * bb(h0[i]); a1 += qf * bb(h1[i]);
            a2 += qf * bb(h2[i]); a3 += qf * bb(h3[i]);
        }
    }
    float* o = SP + (((size_t)(b * NH + h)) * 8 + s) * 1024 + d * 32 + eg * 4;
    o[0] = a0; o[1] = a1; o[2] = a2; o[3] = a3;
}

// ================ combine partials + softmax -> Aca[b][h][d][e] ================
__global__ __launch_bounds__(256) void k_ca_soft(const float* __restrict__ SP, float* __restrict__ Aca) {
    int bh = blockIdx.x;
    const float* Sp = SP + (size_t)bh * 8192;
    int t = threadIdx.x, e = t & 31, sub = t >> 5;
#pragma unroll
    for (int i = 0; i < 4; ++i) {
        int idx = (i * 8 + sub) * 32 + e;
        float v = 0.f;
#pragma unroll
        for (int s = 0; s < 8; ++s) v += Sp[s * 1024 + idx];
        float m = v;
#pragma unroll
        for (int off = 16; off; off >>= 1) m = fmaxf(m, __shfl_xor(m, off, 32));
        float ex = __expf(v - m);
        float sm = ex;
#pragma unroll
        for (int off = 16; off; off >>= 1) sm += __shfl_xor(sm, off, 32);
        Aca[(size_t)bh * 1024 + idx] = ex / sm;
    }
}

// ================ apply: XCAb[b][n][h*32+d] = sum_e Aca[d][e] * v[e][n]  (bf16 out) ================
__global__ __launch_bounds__(256) void k_ca_apply(const u16* __restrict__ Tb, const float* __restrict__ Aca,
                                                  u16* __restrict__ XCAb) {
    int n0 = blockIdx.x * 256, h = blockIdx.y, b = blockIdx.z;
    __shared__ float Ae[32][32];  // [e][d]
    const float* Ab = Aca + ((size_t)b * NH + h) * 1024;
    for (int u = threadIdx.x; u < 1024; u += 256) { int d = u >> 5, e = u & 31; Ae[e][d] = Ab[u]; }
    __syncthreads();
    int n = n0 + threadIdx.x;
    const u16* V = Tb + ((size_t)b * 768 + 512 + h * 32) * N_ + n;
    float acc[32];
#pragma unroll
    for (int d = 0; d < 32; ++d) acc[d] = 0.f;
#pragma unroll
    for (int e = 0; e < 32; ++e) {
        float v = bb(V[(size_t)e * N_]);
#pragma unroll
        for (int dg = 0; dg < 8; ++dg) {
            float4 a4 = *(const float4*)&Ae[e][dg * 4];
            acc[dg * 4 + 0] += a4.x * v; acc[dg * 4 + 1] += a4.y * v;
            acc[dg * 4 + 2] += a4.z * v; acc[dg * 4 + 3] += a4.w * v;
        }
    }
    u16* o = XCAb + ((size_t)b * N_ + n) * C_ + h * 32;
#pragma unroll
    for (int dg = 0; dg < 8; ++dg) {
        ushort4 pk;
        pk.x = f2bf(acc[dg * 4 + 0]); pk.y = f2bf(acc[dg * 4 + 1]);
        pk.z = f2bf(acc[dg * 4 + 2]); pk.w = f2bf(acc[dg * 4 + 3]);
        *(ushort4*)(o + dg * 4) = pk;
    }
}

// ================ out2 MFMA + residual: ATT fp32 [c][n], ATTp bf16 padded [n][c] ================
__global__ __launch_bounds__(256) void k_out2_mfma(const u16* __restrict__ W2B, const u16* __restrict__ XCAb,
                                                   const float* __restrict__ bias2, const float* __restrict__ g1,
                                                   const float* __restrict__ X, float* __restrict__ ATT,
                                                   u16* __restrict__ ATTp) {
    __shared__ __align__(16) u16 As[2][4096], Bs[2][4096];
    int n0 = blockIdx.x * 128, c0 = blockIdx.y * 128, b = blockIdx.z;
    int tid = threadIdx.x, lane = tid & 63, w = tid >> 6;
    int wm = w & 1, wn = w >> 1, qm = lane >> 4, lm = lane & 15;
    int rs = lane >> 2;
    int swz = (((lane & 3) ^ ((rs >> 1) & 3)) << 3);
    int rd  = ((qm ^ ((lm >> 1) & 3)) << 3);
    const u16* Ab = W2B + (size_t)(c0 + w * 32 + rs) * 256 + swz;
    const u16* Bb = XCAb + ((size_t)b * N_ + n0 + w * 32 + rs) * 256 + swz;
    f32x4 acc[4][4] = {};
    auto stage = [&](int kc, int p) {
        gld16(Ab + kc * 32,            As[p] + w * 1024);
        gld16(Ab + 16 * 256 + kc * 32, As[p] + w * 1024 + 512);
        gld16(Bb + kc * 32,            Bs[p] + w * 1024);
        gld16(Bb + 16 * 256 + kc * 32, Bs[p] + w * 1024 + 512);
    };
    stage(0, 0);
    for (int kc = 0; kc < 8; ++kc) {
        int p = kc & 1;
        __syncthreads();
        if (kc + 1 < 8) stage(kc + 1, p ^ 1);
        frag16 af[4], bf[4];
#pragma unroll
        for (int i = 0; i < 4; ++i) af[i] = *(const frag16*)&As[p][(wm * 64 + i * 16 + lm) * 32 + rd];
#pragma unroll
        for (int j = 0; j < 4; ++j) bf[j] = *(const frag16*)&Bs[p][(wn * 64 + j * 16 + lm) * 32 + rd];
#pragma unroll
        for (int i = 0; i < 4; ++i)
#pragma unroll
            for (int j = 0; j < 4; ++j)
                acc[i][j] = __builtin_amdgcn_mfma_f32_16x16x32_bf16(af[i], bf[j], acc[i][j], 0, 0, 0);
    }
    int c_base = c0 + wm * 64, n_base = n0 + wn * 64;
    const float* xin = X + (size_t)b * CN;
    float* Ao = ATT + (size_t)b * CN;
    u16* Ap = ATTp + (size_t)b * PADV * 256;
    float val[4][4][4];
#pragma unroll
    for (int i = 0; i < 4; ++i)
#pragma unroll
        for (int r = 0; r < 4; ++r) {
            int c = c_base + i * 16 + qm * 4 + r;
            float gv = g1[c], bi = bias2[c];
#pragma unroll
            for (int j = 0; j < 4; ++j) {
                int n = n_base + j * 16 + lm;
                float v = xin[(size_t)c * N_ + n] + gv * (acc[i][j][r] + bi);
                val[i][j][r] = v;
                Ao[(size_t)c * N_ + n] = v;
            }
        }
#pragma unroll
    for (int j = 0; j < 4; ++j) {
        int n = n_base + j * 16 + lm;
        int pr = padrow(n);
#pragma unroll
        for (int i = 0; i < 4; ++i) {
            ushort4 pk;
            pk.x = f2bf(val[i][j][0]); pk.y = f2bf(val[i][j][1]);
            pk.z = f2bf(val[i][j][2]); pk.w = f2bf(val[i][j][3]);
            *(ushort4*)&Ap[(size_t)pr * 256 + c_base + i * 16 + qm * 4] = pk;
        }
    }
}

// ================ conv 3^3 MFMA implicit GEMM, split-K=3, double-buffered ================
__global__ __launch_bounds__(256) void k_conv_mfma(const u16* __restrict__ WT2, const u16* __restrict__ ATTp,
                                                   float* __restrict__ Pk) {
    __shared__ __align__(16) u16 As[2][4096], Bs[2][4096];
    int n0 = blockIdx.x * 128;
    int co0 = (blockIdx.y & 1) * 128, ks = blockIdx.y >> 1;   // y in [0,6)
    int b = blockIdx.z;
    int t0 = ks * 9;
    int tid = threadIdx.x, lane = tid & 63, w = tid >> 6;
    int wm = w & 1, wn = w >> 1, qm = lane >> 4, lm = lane & 15;
    int rs = lane >> 2;
    int swz = (((lane & 3) ^ ((rs >> 1) & 3)) << 3);
    int rd  = ((qm ^ ((lm >> 1) & 3)) << 3);
    int pr0 = padrow(n0 + w * 32 + rs);
    int pr1 = padrow(n0 + w * 32 + 16 + rs);
    const u16* Apb = ATTp + (size_t)b * PADV * 256;
    f32x4 acc[4][4] = {};
    auto stage = [&](int kt, int p) {
        int tap = t0 + (kt >> 3), kc = kt & 7;
        int dz = tap / 9 - 1, dy = (tap / 3) % 3 - 1, dx = tap % 3 - 1;
        int toff = dz * 324 + dy * 18 + dx;
        const u16* Aa = WT2 + ((size_t)tap * 256 + co0 + w * 32 + rs) * 256 + kc * 32 + swz;
        gld16(Aa,            As[p] + w * 1024);
        gld16(Aa + 16 * 256, As[p] + w * 1024 + 512);
        gld16(Apb + (size_t)(pr0 + toff) * 256 + kc * 32 + swz, Bs[p] + w * 1024);
        gld16(Apb + (size_t)(pr1 + toff) * 256 + kc * 32 + swz, Bs[p] + w * 1024 + 512);
    };
    stage(0, 0);
    for (int kt = 0; kt < 72; ++kt) {
        int p = kt & 1;
        __syncthreads();
        if (kt + 1 < 72) stage(kt + 1, p ^ 1);
        frag16 af[4], bf[4];
#pragma unroll
        for (int i = 0; i < 4; ++i) af[i] = *(const frag16*)&As[p][(wm * 64 + i * 16 + lm) * 32 + rd];
#pragma unroll
        for (int j = 0; j < 4; ++j) bf[j] = *(const frag16*)&Bs[p][(wn * 64 + j * 16 + lm) * 32 + rd];
#pragma unroll
        for (int i = 0; i < 4; ++i)
#pragma unroll
            for (int j = 0; j < 4; ++j)
                acc[i][j] = __builtin_amdgcn_mfma_f32_16x16x32_bf16(af[i], bf[j], acc[i][j], 0, 0, 0);
    }
    float* Pb = Pk + ((size_t)(ks * B_ + b) * C_ + co0 + wm * 64) * N_ + n0 + wn * 64;
#pragma unroll
    for (int i = 0; i < 4; ++i)
#pragma unroll
        for (int j = 0; j < 4; ++j)
#pragma unroll
            for (int r = 0; r < 4; ++r)
                Pb[(size_t)(i * 16 + qm * 4 + r) * N_ + j * 16 + lm] = acc[i][j][r];
}

// ================ combine split-K (in place into slice 0 = Y) + batch mean/var partials ============
__global__ __launch_bounds__(256) void k_gn_reduce(float* __restrict__ Pk, float* __restrict__ RED) {
    int blk = blockIdx.x, b = blockIdx.y;
    size_t base = (size_t)b * CN + (size_t)blk * 16384;
    float* p0 = Pk + base;
    const float* p1 = Pk + BCN + base;
    const float* p2 = Pk + (size_t)2 * BCN + base;
    float s = 0.f, q = 0.f;
    for (int u = threadIdx.x * 4; u < 16384; u += 1024) {
        float4 a = *(const float4*)&p0[u];
        float4 c1 = *(const float4*)&p1[u];
        float4 c2 = *(const float4*)&p2[u];
        a.x += c1.x + c2.x; a.y += c1.y + c2.y; a.z += c1.z + c2.z; a.w += c1.w + c2.w;
        *(float4*)&p0[u] = a;
        s += a.x + a.y + a.z + a.w;
        q += a.x * a.x + a.y * a.y + a.z * a.z + a.w * a.w;
    }
#pragma unroll
    for (int off = 32; off; off >>= 1) { s += __shfl_down(s, off); q += __shfl_down(q, off); }
    __shared__ float rs_[4], rq[4];
    int lane = threadIdx.x & 63, wv = threadIdx.x >> 6;
    if (!lane) { rs_[wv] = s; rq[wv] = q; }
    __syncthreads();
    if (threadIdx.x == 0) {
        RED[((size_t)b * 64 + blk) * 2 + 0] = rs_[0] + rs_[1] + rs_[2] + rs_[3];
        RED[((size_t)b * 64 + blk) * 2 + 1] = rq[0] + rq[1] + rq[2] + rq[3];
    }
}

__global__ void k_gn_finalize(const float* __restrict__ RED, float* __restrict__ MU) {
    int b = blockIdx.x;
    float s = RED[((size_t)b * 64 + threadIdx.x) * 2 + 0];
    float q = RED[((size_t)b * 64 + threadIdx.x) * 2 + 1];
#pragma unroll
    for (int off = 32; off; off >>= 1) { s += __shfl_down(s, off); q += __shfl_down(q, off); }
    if (threadIdx.x == 0) {
        float inv = 1.0f / (float)CN;
        float mu = s * inv, var = q * inv - mu * mu;
        MU[b * 2 + 0] = mu;
        MU[b * 2 + 1] = rsqrtf(var + 1e-5f);
    }
}

// ================ normalize + affine + residual + leaky relu ================
__global__ __launch_bounds__(256) void k_final(const float* __restrict__ Y, const float* __restrict__ ATT,
                                               const float* __restrict__ MU, const float* __restrict__ gw,
                                               const float* __restrict__ gb, float* __restrict__ out) {
    int i = blockIdx.x * 256 + threadIdx.x;
    int b = i >> 20;
    int c = (i >> 12) & 255;
    float mu = MU[b * 2], rstd = MU[b * 2 + 1];
    float v = (Y[i] - mu) * rstd * gw[c] + gb[c] + ATT[i];
    out[i] = v >= 0.f ? v : 0.01f * v;
}

extern "C" void kernel_launch(void* const* d_in, const int* in_sizes, int n_in,
                              void* d_out, int out_size, void* d_ws, size_t ws_size,
                              hipStream_t stream) {
    const float* x      = (const float*)d_in[0];
    const float* Wqkvv  = (const float*)d_in[1];
    // d_in[2] W_out, d_in[3] b_out, d_in[10] index_sample: DEAD in reference
    const float* W_out2 = (const float*)d_in[4];
    const float* b_out2 = (const float*)d_in[5];
    const float* gamma1 = (const float*)d_in[6];
    const float* conv_w = (const float*)d_in[7];
    const float* gn_w   = (const float*)d_in[8];
    const float* gn_b   = (const float*)d_in[9];
    float* out = (float*)d_out;
    float* ws = (float*)d_ws;

    u16*   Tb   = (u16*)(ws + OFF_TB);
    float* Aca  = ws + OFF_ACA;
    u16*   XCAb = (u16*)(ws + OFF_XCAB);
    float* Pk   = ws + OFF_PK;       // aliases Tb/Aca/XCAb (all dead before conv)
    float* Y    = Pk;                // split-K combined in place into slice 0
    float* ATT  = ws + OFF_ATT;
    u16*   ATTp = (u16*)(ws + OFF_ATTP);
    u16*   WT2  = (u16*)(ws + OFF_WT2);
    u16*   W2B  = (u16*)(ws + OFF_W2B);
    u16*   Wqb  = (u16*)(ws + OFF_WQB);
    u16*   XT   = (u16*)(ws + OFF_XT);
    float* SP   = ws + OFF_SP;
    float* RED  = ws + OFF_RED;
    float* MU   = ws + OFF_MU;

    k_prep_w2   <<<6912, 256, 0, stream>>>(conv_w, WT2);
    k_prep_w2b  <<<dim3(8, 8), 256, 0, stream>>>(W_out2, W2B);
    k_prep_wq   <<<768, 256, 0, stream>>>(Wqkvv, Wqb);
    k_prep_x    <<<dim3(N_ / 32, C_ / 32, B_), 256, 0, stream>>>(x, XT);
    k_zero_pad  <<<5832, 256, 0, stream>>>((u32*)ATTp);
    k_qkv_mfma  <<<dim3(N_ / 128, 768 / 128, B_), 256, 0, stream>>>(Wqb, XT, Tb);
    k_l2norm    <<<B_ * 512, 256, 0, stream>>>(Tb);
    k_ca_part   <<<dim3(8, NH, B_), 256, 0, stream>>>(Tb, SP);
    k_ca_soft   <<<B_ * NH, 256, 0, stream>>>(SP, Aca);
    k_ca_apply  <<<dim3(N_ / 256, NH, B_), 256, 0, stream>>>(Tb, Aca, XCAb);
    k_out2_mfma <<<dim3(N_ / 128, C_ / 128, B_), 256, 0, stream>>>(W2B, XCAb, b_out2, gamma1, x, ATT, ATTp);
    k_conv_mfma <<<dim3(N_ / 128, 6, B_), 256, 0, stream>>>(WT2, ATTp, Pk);
    k_gn_reduce <<<dim3(64, B_), 256, 0, stream>>>(Pk, RED);
    k_gn_finalize<<<B_, 64, 0, stream>>>(RED, MU);
    k_final     <<<(B_ * CN) / 256, 256, 0, stream>>>(Y, ATT, MU, gn_w, gn_b, out);
}

// Round 5
// 191.390 us; speedup vs baseline: 4.9182x; 1.2296x over previous
//
#include <hip/hip_runtime.h>
#include <hip/hip_bf16.h>
#include <stdint.h>

// B=2, C=256, H=W=D=16 -> N=4096, nh=8, dh=32. ALL float32 I/O.
// Reference dead code: x_sa path (top-k, index_sample, W_out, b_out, v_sa) — epa = x_ca only.
// Round 5: conv/qkv/out2 use K=64 LDS chunks (32 MFMA per barrier), full unroll
// (no per-iter divides), 8-slot XOR swizzle; 17 -> 9 dispatches; ATT as bf16.

#define B_ 2
#define C_ 256
#define N_ 4096
#define NH 8
#define PADV 5832                    // 18^3 zero-padded spatial volume
#define CN  (C_*N_)                  // 2^20
#define BCN (B_*CN)

typedef unsigned short u16;
typedef unsigned int   u32;

using frag16 = __attribute__((ext_vector_type(8))) short;   // 8 bf16 = 4 VGPR
using f32x4  = __attribute__((ext_vector_type(4))) float;   // MFMA C/D

__device__ __forceinline__ u16 f2bf(float f) {
    u32 u = __float_as_uint(f);
    u += 0x7fff + ((u >> 16) & 1);
    return (u16)(u >> 16);
}
__device__ __forceinline__ float bb(u16 h) { return __uint_as_float((u32)h << 16); }
__device__ __forceinline__ void gld16(const void* g, void* l) {
    __builtin_amdgcn_global_load_lds((const __attribute__((address_space(1))) u32*)g,
                                     (__attribute__((address_space(3))) u32*)l, 16, 0, 0);
}
__device__ __forceinline__ int padrow(int n) {
    int z = n >> 8, y = (n >> 4) & 15, x = n & 15;
    return (z + 1) * 324 + (y + 1) * 18 + (x + 1);
}

// ---- workspace (float units), ~43.6 MB
#define OFF_TB    0            // bf16 [B][768][N]; Pk aliases this region later
#define OFF_SP    3145728      // fp32 [B][NH][8][1024]
#define OFF_XCAB  3276800      // bf16 [B][N][C]
#define OFF_PK    0            // fp32 [3][B][C][N] = 6291456 fl (aliases TB/SP/XCAB, all dead)
#define OFF_ATTB  6291456      // bf16 [B][C][N]
#define OFF_ATTP  7340032      // bf16 [B][PADV][C]
#define OFF_WT2   8833024      // bf16 [27][co][ci]
#define OFF_W2B   9717760      // bf16 [c][c']
#define OFF_WQB   9750528      // bf16 [j][c]
#define OFF_XT    9848832      // bf16 [B][N][C]
#define OFF_RED   10897408     // fp32 [B][64][2]
 
// ================ merged prep: w2 transpose, w2b, wq, x transpose, ATTp zero ================
__global__ __launch_bounds__(256) void k_prep(const float* __restrict__ CW, const float* __restrict__ W2,
                                              const float* __restrict__ Wq, const float* __restrict__ X,
                                              u16* __restrict__ WT2, u16* __restrict__ W2B,
                                              u16* __restrict__ Wqb, u16* __restrict__ XT,
                                              u32* __restrict__ APz) {
    __shared__ float ts[32][33];
    int blk = blockIdx.x, tid = threadIdx.x;
    if (blk < 6912) {                                   // WT2[t][co][ci] = conv_w[co][ci][t]
        int o = blk * 256 + tid;
        int ci = o & 255, co = (o >> 8) & 255, t = o >> 16;
        WT2[o] = f2bf(CW[((size_t)co * 256 + ci) * 27 + t]);
    } else if (blk < 6976) {                            // W2B[c][p] = W2[p][c]
        int bi = blk - 6912; int c0 = (bi & 7) * 32, p0 = (bi >> 3) * 32;
        int tx = tid & 31, ty = tid >> 5;
#pragma unroll
        for (int i = 0; i < 4; ++i) ts[ty + i * 8][tx] = W2[(size_t)(p0 + ty + i * 8) * 256 + c0 + tx];
        __syncthreads();
#pragma unroll
        for (int i = 0; i < 4; ++i) W2B[(size_t)(c0 + ty + i * 8) * 256 + p0 + tx] = f2bf(ts[tx][ty + i * 8]);
    } else if (blk < 7744) {                            // Wqb[j][c] = Wq[c][j]
        int o = (blk - 6976) * 256 + tid;
        int c = o & 255, j = o >> 8;
        Wqb[o] = f2bf(Wq[(size_t)c * 1024 + j]);
    } else if (blk < 9792) {                            // XT[b][n][c] = x[b][c][n]
        int idx = blk - 7744;
        int n0 = (idx & 127) * 32, c0 = ((idx >> 7) & 7) * 32, b = idx >> 10;
        int tx = tid & 31, ty = tid >> 5;
        const float* Xb = X + (size_t)b * CN;
#pragma unroll
        for (int i = 0; i < 4; ++i) ts[ty + i * 8][tx] = Xb[(size_t)(c0 + ty + i * 8) * N_ + n0 + tx];
        __syncthreads();
        u16* Xo = XT + (size_t)b * N_ * C_;
#pragma unroll
        for (int i = 0; i < 4; ++i) Xo[(size_t)(n0 + ty + i * 8) * C_ + c0 + tx] = f2bf(ts[tx][ty + i * 8]);
    } else {                                            // zero ATTp
        APz[(size_t)(blk - 9792) * 256 + tid] = 0;
    }
}

// ================ QKV MFMA, K=64 chunks: Tb[b][j][n] = sum_c Wqb[j][c]*XT[b][n][c] ================
__global__ __launch_bounds__(256) void k_qkv_mfma(const u16* __restrict__ Wqb, const u16* __restrict__ XT,
                                                  u16* __restrict__ Tb) {
    __shared__ __align__(16) u16 As[2][8192], Bs[2][8192];
    int n0 = blockIdx.x * 128, j0 = blockIdx.y * 128, b = blockIdx.z;
    int tid = threadIdx.x, lane = tid & 63, w = tid >> 6;
    int wm = w & 1, wn = w >> 1, qm = lane >> 4, lm = lane & 15;
    int srow = lane >> 3;
    int sperm = (((lane & 7) ^ srow) << 3);
    const u16* aB = Wqb + ((size_t)(j0 + w * 32 + srow) << 8) + sperm;
    const u16* bB = XT + ((size_t)(b * N_ + n0 + w * 32 + srow) << 8) + sperm;
    int rdp = ((lm & 7) << 3);                          // XOR key *8 (u16)
    f32x4 acc[4][4] = {};
    auto stg = [&](int p, int kc) {
#pragma unroll
        for (int i = 0; i < 4; ++i) {
            gld16(aB + i * 2048 + kc * 64, &As[p][w * 2048 + i * 512]);
            gld16(bB + i * 2048 + kc * 64, &Bs[p][w * 2048 + i * 512]);
        }
    };
    stg(0, 0);
#pragma unroll
    for (int kt = 0; kt < 4; ++kt) {
        int p = kt & 1;
        __syncthreads();
        if (kt < 3) stg(p ^ 1, kt + 1);
#pragma unroll
        for (int c2 = 0; c2 < 2; ++c2) {
            frag16 af[4], bf[4];
#pragma unroll
            for (int i = 0; i < 4; ++i)
                af[i] = *(const frag16*)&As[p][(wm * 64 + i * 16 + lm) * 64 + ((((c2 * 4 + qm) << 3) ^ rdp))];
#pragma unroll
            for (int j = 0; j < 4; ++j)
                bf[j] = *(const frag16*)&Bs[p][(wn * 64 + j * 16 + lm) * 64 + ((((c2 * 4 + qm) << 3) ^ rdp))];
#pragma unroll
            for (int i = 0; i < 4; ++i)
#pragma unroll
                for (int j = 0; j < 4; ++j)
                    acc[i][j] = __builtin_amdgcn_mfma_f32_16x16x32_bf16(af[i], bf[j], acc[i][j], 0, 0, 0);
        }
    }
    u16* To = Tb + ((size_t)b * 768 + j0 + wm * 64) * N_ + n0 + wn * 64;
#pragma unroll
    for (int i = 0; i < 4; ++i)
#pragma unroll
        for (int j = 0; j < 4; ++j)
#pragma unroll
            for (int r = 0; r < 4; ++r)
                To[(size_t)(i * 16 + qm * 4 + r) * N_ + j * 16 + lm] = f2bf(acc[i][j][r]);
}

// ================ l2norm over n for q,k rows ================
__global__ __launch_bounds__(256) void k_l2norm(u16* __restrict__ Tb) {
    int bj = blockIdx.x; int b = bj >> 9, j = bj & 511;
    u16* row = Tb + ((size_t)b * 768 + j) * N_;
    float s = 0.f;
    for (int u = threadIdx.x * 8; u < N_; u += 2048) {
        uint4 vv = *(const uint4*)(row + u);
        const u16* h = (const u16*)&vv;
#pragma unroll
        for (int i = 0; i < 8; ++i) { float f = bb(h[i]); s += f * f; }
    }
#pragma unroll
    for (int off = 32; off; off >>= 1) s += __shfl_down(s, off);
    __shared__ float rs_[4]; __shared__ float rtot;
    int lane = threadIdx.x & 63, wv = threadIdx.x >> 6;
    if (!lane) rs_[wv] = s;
    __syncthreads();
    if (threadIdx.x == 0) rtot = 1.0f / fmaxf(sqrtf(rs_[0] + rs_[1] + rs_[2] + rs_[3]), 1e-12f);
    __syncthreads();
    float rn = rtot;
    for (int u = threadIdx.x * 8; u < N_; u += 2048) {
        uint4 vv = *(const uint4*)(row + u);
        u16* h = (u16*)&vv;
#pragma unroll
        for (int i = 0; i < 8; ++i) h[i] = f2bf(bb(h[i]) * rn);
        *(uint4*)(row + u) = vv;
    }
}

// ================ ca scores partials: SP[b][h][s][d*32+e] ================
__global__ __launch_bounds__(256) void k_ca_part(const u16* __restrict__ Tb, float* __restrict__ SP) {
    int s = blockIdx.x, h = blockIdx.y, b = blockIdx.z;
    int t = threadIdx.x, d = t & 31, eg = t >> 5;
    const u16* Q  = Tb + ((size_t)b * 768 + h * 32 + d) * N_ + s * 512;
    const u16* K0 = Tb + ((size_t)b * 768 + 256 + h * 32 + eg * 4) * N_ + s * 512;
    float a0 = 0.f, a1 = 0.f, a2 = 0.f, a3 = 0.f;
    for (int u = 0; u < 512; u += 8) {
        uint4 qv = *(const uint4*)(Q + u);
        uint4 k0 = *(const uint4*)(K0 + u);
        uint4 k1 = *(const uint4*)(K0 + (size_t)N_ + u);
        uint4 k2 = *(const uint4*)(K0 + (size_t)2 * N_ + u);
        uint4 k3 = *(const uint4*)(K0 + (size_t)3 * N_ + u);
        const u16 *qh = (const u16*)&qv, *h0 = (const u16*)&k0, *h1 = (const u16*)&k1,
                  *h2 = (const u16*)&k2, *h3 = (const u16*)&k3;
#pragma unroll
        for (int i = 0; i < 8; ++i) {
            float qf = bb(qh[i]);
            a0 += qf * bb(h0[i]); a1 += qf * bb(h1[i]);
            a2 += qf * bb(h2[i]); a3 += qf * bb(h3[i]);
        }
    }
    float* o = SP + (((size_t)(b * NH + h)) * 8 + s) * 1024 + d * 32 + eg * 4;
    o[0] = a0; o[1] = a1; o[2] = a2; o[3] = a3;
}

// ================ ca softmax (from SP) + apply: XCAb[b][n][h*32+d] ================
__global__ __launch_bounds__(256) void k_ca_apply(const u16* __restrict__ Tb, const float* __restrict__ SP,
                                                  u16* __restrict__ XCAb) {
    int n0 = blockIdx.x * 256, h = blockIdx.y, b = blockIdx.z;
    __shared__ float raw[1024];
    __shared__ float Ae[32][32];  // [e][d]
    int tid = threadIdx.x;
    const float* Sp = SP + ((size_t)(b * NH + h)) * 8192;
    for (int u = tid; u < 1024; u += 256) {
        float v = 0.f;
#pragma unroll
        for (int s = 0; s < 8; ++s) v += Sp[s * 1024 + u];
        raw[u] = v;
    }
    __syncthreads();
    if (tid < 32) {                    // row d = tid: softmax over e
        float m = -1e30f;
#pragma unroll
        for (int e = 0; e < 32; ++e) m = fmaxf(m, raw[tid * 32 + e]);
        float ex[32]; float sm = 0.f;
#pragma unroll
        for (int e = 0; e < 32; ++e) { ex[e] = __expf(raw[tid * 32 + e] - m); sm += ex[e]; }
        float rinv = 1.0f / sm;
#pragma unroll
        for (int e = 0; e < 32; ++e) Ae[e][tid] = ex[e] * rinv;
    }
    __syncthreads();
    int n = n0 + tid;
    const u16* V = Tb + ((size_t)b * 768 + 512 + h * 32) * N_ + n;
    float acc[32];
#pragma unroll
    for (int d = 0; d < 32; ++d) acc[d] = 0.f;
#pragma unroll
    for (int e = 0; e < 32; ++e) {
        float v = bb(V[(size_t)e * N_]);
#pragma unroll
        for (int dg = 0; dg < 8; ++dg) {
            float4 a4 = *(const float4*)&Ae[e][dg * 4];
            acc[dg * 4 + 0] += a4.x * v; acc[dg * 4 + 1] += a4.y * v;
            acc[dg * 4 + 2] += a4.z * v; acc[dg * 4 + 3] += a4.w * v;
        }
    }
    u16* o = XCAb + ((size_t)b * N_ + n) * C_ + h * 32;
#pragma unroll
    for (int dg = 0; dg < 8; ++dg) {
        ushort4 pk;
        pk.x = f2bf(acc[dg * 4 + 0]); pk.y = f2bf(acc[dg * 4 + 1]);
        pk.z = f2bf(acc[dg * 4 + 2]); pk.w = f2bf(acc[dg * 4 + 3]);
        *(ushort4*)(o + dg * 4) = pk;
    }
}

// ================ out2 MFMA (K=64 chunks) + residual -> ATTb bf16 [c][n], ATTp bf16 [n_pad][c] =====
__global__ __launch_bounds__(256) void k_out2_mfma(const u16* __restrict__ W2B, const u16* __restrict__ XCAb,
                                                   const float* __restrict__ bias2, const float* __restrict__ g1,
                                                   const float* __restrict__ X, u16* __restrict__ ATTb,
                                                   u16* __restrict__ ATTp) {
    __shared__ __align__(16) u16 As[2][8192], Bs[2][8192];
    int n0 = blockIdx.x * 128, c0 = blockIdx.y * 128, b = blockIdx.z;
    int tid = threadIdx.x, lane = tid & 63, w = tid >> 6;
    int wm = w & 1, wn = w >> 1, qm = lane >> 4, lm = lane & 15;
    int srow = lane >> 3;
    int sperm = (((lane & 7) ^ srow) << 3);
    const u16* aB = W2B + ((size_t)(c0 + w * 32 + srow) << 8) + sperm;
    const u16* bB = XCAb + ((size_t)(b * N_ + n0 + w * 32 + srow) << 8) + sperm;
    int rdp = ((lm & 7) << 3);
    f32x4 acc[4][4] = {};
    auto stg = [&](int p, int kc) {
#pragma unroll
        for (int i = 0; i < 4; ++i) {
            gld16(aB + i * 2048 + kc * 64, &As[p][w * 2048 + i * 512]);
            gld16(bB + i * 2048 + kc * 64, &Bs[p][w * 2048 + i * 512]);
        }
    };
    stg(0, 0);
#pragma unroll
    for (int kt = 0; kt < 4; ++kt) {
        int p = kt & 1;
        __syncthreads();
        if (kt < 3) stg(p ^ 1, kt + 1);
#pragma unroll
        for (int c2 = 0; c2 < 2; ++c2) {
            frag16 af[4], bf[4];
#pragma unroll
            for (int i = 0; i < 4; ++i)
                af[i] = *(const frag16*)&As[p][(wm * 64 + i * 16 + lm) * 64 + ((((c2 * 4 + qm) << 3) ^ rdp))];
#pragma unroll
            for (int j = 0; j < 4; ++j)
                bf[j] = *(const frag16*)&Bs[p][(wn * 64 + j * 16 + lm) * 64 + ((((c2 * 4 + qm) << 3) ^ rdp))];
#pragma unroll
            for (int i = 0; i < 4; ++i)
#pragma unroll
                for (int j = 0; j < 4; ++j)
                    acc[i][j] = __builtin_amdgcn_mfma_f32_16x16x32_bf16(af[i], bf[j], acc[i][j], 0, 0, 0);
        }
    }
    int c_base = c0 + wm * 64, n_base = n0 + wn * 64;
    const float* xin = X + (size_t)b * CN;
    u16* Ao = ATTb + (size_t)b * CN;
    u16* Ap = ATTp + ((size_t)b * PADV << 8);
    float val[4][4][4];
#pragma unroll
    for (int i = 0; i < 4; ++i)
#pragma unroll
        for (int r = 0; r < 4; ++r) {
            int c = c_base + i * 16 + qm * 4 + r;
            float gv = g1[c], bi = bias2[c];
#pragma unroll
            for (int j = 0; j < 4; ++j) {
                int n = n_base + j * 16 + lm;
                float v = xin[(size_t)c * N_ + n] + gv * (acc[i][j][r] + bi);
                val[i][j][r] = v;
                Ao[(size_t)c * N_ + n] = f2bf(v);
            }
        }
#pragma unroll
    for (int j = 0; j < 4; ++j) {
        int n = n_base + j * 16 + lm;
        int pr = padrow(n);
#pragma unroll
        for (int i = 0; i < 4; ++i) {
            ushort4 pk;
            pk.x = f2bf(val[i][j][0]); pk.y = f2bf(val[i][j][1]);
            pk.z = f2bf(val[i][j][2]); pk.w = f2bf(val[i][j][3]);
            *(ushort4*)&Ap[((size_t)pr << 8) + c_base + i * 16 + qm * 4] = pk;
        }
    }
}

// ================ conv 3^3 MFMA, split-K=3, K=64 chunks, fully unrolled ================
__global__ __launch_bounds__(256) void k_conv_mfma(const u16* __restrict__ WT2, const u16* __restrict__ ATTp,
                                                   float* __restrict__ Pk) {
    __shared__ __align__(16) u16 As[2][8192], Bs[2][8192];
    int n0 = blockIdx.x * 128;
    int co0 = (blockIdx.y & 1) * 128, ks = blockIdx.y >> 1;
    int b = blockIdx.z;
    int tid = threadIdx.x, lane = tid & 63, w = tid >> 6;
    int wm = w & 1, wn = w >> 1, qm = lane >> 4, lm = lane & 15;
    int srow = lane >> 3;
    int sperm = (((lane & 7) ^ srow) << 3);
    const u16* aB = WT2 + (((size_t)ks * 9 * 256 + co0 + w * 32 + srow) << 8) + sperm;
    int prA[4];
#pragma unroll
    for (int i = 0; i < 4; ++i) prA[i] = padrow(n0 + w * 32 + i * 8 + srow) << 8;
    const u16* bB = ATTp + ((size_t)b * PADV << 8) + ((ks - 1) * 324 << 8) + sperm;
    int rdp = ((lm & 7) << 3);
    f32x4 acc[4][4] = {};
    auto stg = [&](int p, int kt) {
        int tap9 = kt >> 2, kc = kt & 3;
        int K9 = ((tap9 / 3) - 1) * 18 + (tap9 % 3 - 1);   // compile-time under full unroll
#pragma unroll
        for (int i = 0; i < 4; ++i) {
            gld16(aB + (size_t)tap9 * 65536 + i * 2048 + kc * 64, &As[p][w * 2048 + i * 512]);
            gld16(bB + prA[i] + K9 * 256 + kc * 64,              &Bs[p][w * 2048 + i * 512]);
        }
    };
    stg(0, 0);
#pragma unroll
    for (int kt = 0; kt < 36; ++kt) {
        int p = kt & 1;
        __syncthreads();
        if (kt < 35) stg(p ^ 1, kt + 1);
#pragma unroll
        for (int c2 = 0; c2 < 2; ++c2) {
            frag16 af[4], bf[4];
#pragma unroll
            for (int i = 0; i < 4; ++i)
                af[i] = *(const frag16*)&As[p][(wm * 64 + i * 16 + lm) * 64 + ((((c2 * 4 + qm) << 3) ^ rdp))];
#pragma unroll
            for (int j = 0; j < 4; ++j)
                bf[j] = *(const frag16*)&Bs[p][(wn * 64 + j * 16 + lm) * 64 + ((((c2 * 4 + qm) << 3) ^ rdp))];
#pragma unroll
            for (int i = 0; i < 4; ++i)
#pragma unroll
                for (int j = 0; j < 4; ++j)
                    acc[i][j] = __builtin_amdgcn_mfma_f32_16x16x32_bf16(af[i], bf[j], acc[i][j], 0, 0, 0);
        }
    }
    float* Pb = Pk + ((size_t)(ks * B_ + b) * C_ + co0 + wm * 64) * N_ + n0 + wn * 64;
#pragma unroll
    for (int i = 0; i < 4; ++i)
#pragma unroll
        for (int j = 0; j < 4; ++j)
#pragma unroll
            for (int r = 0; r < 4; ++r)
                Pb[(size_t)(i * 16 + qm * 4 + r) * N_ + j * 16 + lm] = acc[i][j][r];
}

// ================ combine split-K in place (slice 0 = Y) + batch mean/var partials ================
__global__ __launch_bounds__(256) void k_gn_reduce(float* __restrict__ Pk, float* __restrict__ RED) {
    int blk = blockIdx.x, b = blockIdx.y;
    size_t base = (size_t)b * CN + (size_t)blk * 16384;
    float* p0 = Pk + base;
    const float* p1 = Pk + BCN + base;
    const float* p2 = Pk + (size_t)2 * BCN + base;
    float s = 0.f, q = 0.f;
    for (int u = threadIdx.x * 4; u < 16384; u += 1024) {
        float4 a = *(const float4*)&p0[u];
        float4 c1 = *(const float4*)&p1[u];
        float4 c2 = *(const float4*)&p2[u];
        a.x += c1.x + c2.x; a.y += c1.y + c2.y; a.z += c1.z + c2.z; a.w += c1.w + c2.w;
        *(float4*)&p0[u] = a;
        s += a.x + a.y + a.z + a.w;
        q += a.x * a.x + a.y * a.y + a.z * a.z + a.w * a.w;
    }
#pragma unroll
    for (int off = 32; off; off >>= 1) { s += __shfl_down(s, off); q += __shfl_down(q, off); }
    __shared__ float rs_[4], rq[4];
    int lane = threadIdx.x & 63, wv = threadIdx.x >> 6;
    if (!lane) { rs_[wv] = s; rq[wv] = q; }
    __syncthreads();
    if (threadIdx.x == 0) {
        RED[((size_t)b * 64 + blk) * 2 + 0] = rs_[0] + rs_[1] + rs_[2] + rs_[3];
        RED[((size_t)b * 64 + blk) * 2 + 1] = rq[0] + rq[1] + rq[2] + rq[3];
    }
}

// ================ finalize: in-block RED reduce + normalize + residual + leaky relu ================
__global__ __launch_bounds__(256) void k_final(const float* __restrict__ Y, const u16* __restrict__ ATTb,
                                               const float* __restrict__ RED, const float* __restrict__ gw,
                                               const float* __restrict__ gb, float* __restrict__ out) {
    int i = blockIdx.x * 256 + threadIdx.x;
    int b = i >> 20;
    int c = (i >> 12) & 255;
    __shared__ float smu[2];
    if (threadIdx.x < 64) {
        float s = RED[((size_t)b * 64 + threadIdx.x) * 2 + 0];
        float q = RED[((size_t)b * 64 + threadIdx.x) * 2 + 1];
#pragma unroll
        for (int off = 32; off; off >>= 1) { s += __shfl_down(s, off); q += __shfl_down(q, off); }
        if (threadIdx.x == 0) {
            float inv = 1.0f / (float)CN;
            float mu = s * inv, var = q * inv - mu * mu;
            smu[0] = mu; smu[1] = rsqrtf(var + 1e-5f);
        }
    }
    __syncthreads();
    float v = (Y[i] - smu[0]) * smu[1] * gw[c] + gb[c] + bb(ATTb[i]);
    out[i] = v >= 0.f ? v : 0.01f * v;
}

extern "C" void kernel_launch(void* const* d_in, const int* in_sizes, int n_in,
                              void* d_out, int out_size, void* d_ws, size_t ws_size,
                              hipStream_t stream) {
    const float* x      = (const float*)d_in[0];
    const float* Wqkvv  = (const float*)d_in[1];
    // d_in[2] W_out, d_in[3] b_out, d_in[10] index_sample: DEAD in reference
    const float* W_out2 = (const float*)d_in[4];
    const float* b_out2 = (const float*)d_in[5];
    const float* gamma1 = (const float*)d_in[6];
    const float* conv_w = (const float*)d_in[7];
    const float* gn_w   = (const float*)d_in[8];
    const float* gn_b   = (const float*)d_in[9];
    float* out = (float*)d_out;
    float* ws = (float*)d_ws;

    u16*   Tb   = (u16*)(ws + OFF_TB);
    float* SP   = ws + OFF_SP;
    u16*   XCAb = (u16*)(ws + OFF_XCAB);
    float* Pk   = ws + OFF_PK;       // aliases Tb/SP/XCAb (dead before conv)
    float* Y    = Pk;
    u16*   ATTb = (u16*)(ws + OFF_ATTB);
    u16*   ATTp = (u16*)(ws + OFF_ATTP);
    u16*   WT2  = (u16*)(ws + OFF_WT2);
    u16*   W2B  = (u16*)(ws + OFF_W2B);
    u16*   Wqb  = (u16*)(ws + OFF_WQB);
    u16*   XT   = (u16*)(ws + OFF_XT);
    float* RED  = ws + OFF_RED;

    k_prep      <<<15624, 256, 0, stream>>>(conv_w, W_out2, Wqkvv, x, WT2, W2B, Wqb, XT, (u32*)ATTp);
    k_qkv_mfma  <<<dim3(N_ / 128, 6, B_), 256, 0, stream>>>(Wqb, XT, Tb);
    k_l2norm    <<<B_ * 512, 256, 0, stream>>>(Tb);
    k_ca_part   <<<dim3(8, NH, B_), 256, 0, stream>>>(Tb, SP);
    k_ca_apply  <<<dim3(N_ / 256, NH, B_), 256, 0, stream>>>(Tb, SP, XCAb);
    k_out2_mfma <<<dim3(N_ / 128, C_ / 128, B_), 256, 0, stream>>>(W2B, XCAb, b_out2, gamma1, x, ATTb, ATTp);
    k_conv_mfma <<<dim3(N_ / 128, 6, B_), 256, 0, stream>>>(WT2, ATTp, Pk);
    k_gn_reduce <<<dim3(64, B_), 256, 0, stream>>>(Pk, RED);
    k_final     <<<(B_ * CN) / 256, 256, 0, stream>>>(Y, ATTb, RED, gn_w, gn_b, out);
}

// Round 6
// 181.212 us; speedup vs baseline: 5.1945x; 1.0562x over previous
//
#include <hip/hip_runtime.h>
#include <hip/hip_bf16.h>
#include <stdint.h>

// B=2, C=256, H=W=D=16 -> N=4096, nh=8, dh=32. ALL float32 I/O.
// Reference dead code: x_sa path (top-k, index_sample, W_out, b_out, v_sa) — epa = x_ca only.
// Round 6: l2norm folded into scores via RSQ atomics; coalesced prep transposes;
// ca_part 32 slices; split-K partials + Y in bf16; 8 dispatches.

#define B_ 2
#define C_ 256
#define N_ 4096
#define NH 8
#define PADV 5832
#define CN  (C_*N_)
#define BCN (B_*CN)

typedef unsigned short u16;
typedef unsigned int   u32;

using frag16 = __attribute__((ext_vector_type(8))) short;
using f32x4  = __attribute__((ext_vector_type(4))) float;

__device__ __forceinline__ u16 f2bf(float f) {
    u32 u = __float_as_uint(f);
    u += 0x7fff + ((u >> 16) & 1);
    return (u16)(u >> 16);
}
__device__ __forceinline__ float bb(u16 h) { return __uint_as_float((u32)h << 16); }
__device__ __forceinline__ void gld16(const void* g, void* l) {
    __builtin_amdgcn_global_load_lds((const __attribute__((address_space(1))) u32*)g,
                                     (__attribute__((address_space(3))) u32*)l, 16, 0, 0);
}
__device__ __forceinline__ int padrow(int n) {
    int z = n >> 8, y = (n >> 4) & 15, x = n & 15;
    return (z + 1) * 324 + (y + 1) * 18 + (x + 1);
}

// ---- workspace (float units), ~43.6 MB
#define OFF_TB    0            // bf16 [B][768][N] raw q,k,v; aliased by PKB after ca_apply
#define OFF_SP    3145728      // fp32 [B][NH][32][1024] score partials
#define OFF_XCAB  3670016      // bf16 [B][N][C]
#define OFF_PKB   0            // bf16 [3][B][C][N] conv partials (alias TB exactly)
#define OFF_Y     3145728      // bf16 [B][C][N] combined conv out (alias SP+XCAB head)
#define OFF_ATTB  6291456      // bf16 [B][C][N]
#define OFF_ATTP  7340032      // bf16 [B][PADV][C]
#define OFF_WT2   8833024      // bf16 [27][co][ci]
#define OFF_W2B   9717760      // bf16 [c][c']
#define OFF_WQB   9750528      // bf16 [j][c], j<768
#define OFF_XT    9848832      // bf16 [B][N][C]
#define OFF_RSQ   10897408     // fp32 [B][512] row sum-of-squares (q,k)
#define OFF_RED   10898432     // fp32 [B][64][2]

// ================ merged prep ================
__global__ __launch_bounds__(256) void k_prep(const float* __restrict__ CW, const float* __restrict__ W2,
                                              const float* __restrict__ Wq, const float* __restrict__ X,
                                              u16* __restrict__ WT2, u16* __restrict__ W2B,
                                              u16* __restrict__ Wqb, u16* __restrict__ XT,
                                              u32* __restrict__ APz, float* __restrict__ RSQ) {
    __shared__ __align__(16) float ls[6912];
    float (*ts)[33] = (float(*)[33])ls;
    int blk = blockIdx.x, tid = threadIdx.x;
    if (blk < 256) {                                    // WT2[t][co][ci] = conv_w[co][ci][t], coalesced
        int co = blk;
        const float* src = CW + (size_t)co * 6912;
        for (int u = tid; u < 6912; u += 256) ls[u] = src[u];
        __syncthreads();
#pragma unroll
        for (int t = 0; t < 27; ++t)
            WT2[(((size_t)t * 256 + co) << 8) + tid] = f2bf(ls[tid * 27 + t]);
    } else if (blk < 320) {                             // W2B[c][p] = W2[p][c]
        int bi = blk - 256; int c0 = (bi & 7) * 32, p0 = (bi >> 3) * 32;
        int tx = tid & 31, ty = tid >> 5;
#pragma unroll
        for (int i = 0; i < 4; ++i) ts[ty + i * 8][tx] = W2[(size_t)(p0 + ty + i * 8) * 256 + c0 + tx];
        __syncthreads();
#pragma unroll
        for (int i = 0; i < 4; ++i) W2B[(size_t)(c0 + ty + i * 8) * 256 + p0 + tx] = f2bf(ts[tx][ty + i * 8]);
    } else if (blk < 512) {                             // Wqb[j][c] = Wq[c][j], j<768, LDS transpose
        int bi = blk - 320; int c0 = (bi & 7) * 32, j0 = (bi >> 3) * 32;
        int tx = tid & 31, ty = tid >> 5;
#pragma unroll
        for (int i = 0; i < 4; ++i) ts[ty + i * 8][tx] = Wq[(size_t)(c0 + ty + i * 8) * 1024 + j0 + tx];
        __syncthreads();
#pragma unroll
        for (int i = 0; i < 4; ++i) Wqb[(size_t)(j0 + ty + i * 8) * 256 + c0 + tx] = f2bf(ts[tx][ty + i * 8]);
    } else if (blk < 2560) {                            // XT[b][n][c] = x[b][c][n]
        int idx = blk - 512;
        int n0 = (idx & 127) * 32, c0 = ((idx >> 7) & 7) * 32, b = idx >> 10;
        int tx = tid & 31, ty = tid >> 5;
        const float* Xb = X + (size_t)b * CN;
#pragma unroll
        for (int i = 0; i < 4; ++i) ts[ty + i * 8][tx] = Xb[(size_t)(c0 + ty + i * 8) * N_ + n0 + tx];
        __syncthreads();
        u16* Xo = XT + (size_t)b * N_ * C_;
#pragma unroll
        for (int i = 0; i < 4; ++i) Xo[(size_t)(n0 + ty + i * 8) * C_ + c0 + tx] = f2bf(ts[tx][ty + i * 8]);
    } else if (blk < 8392) {                            // zero ATTp
        APz[(size_t)(blk - 2560) * 256 + tid] = 0;
    } else {                                            // zero RSQ [B][512] fp32
        ((float4*)RSQ)[tid] = make_float4(0.f, 0.f, 0.f, 0.f);
    }
}

// ================ QKV MFMA, K=64 chunks + RSQ row-sumsq atomics for q,k ================
__global__ __launch_bounds__(256) void k_qkv_mfma(const u16* __restrict__ Wqb, const u16* __restrict__ XT,
                                                  u16* __restrict__ Tb, float* __restrict__ RSQ) {
    __shared__ __align__(16) u16 As[2][8192], Bs[2][8192];
    int n0 = blockIdx.x * 128, j0 = blockIdx.y * 128, b = blockIdx.z;
    int tid = threadIdx.x, lane = tid & 63, w = tid >> 6;
    int wm = w & 1, wn = w >> 1, qm = lane >> 4, lm = lane & 15;
    int srow = lane >> 3;
    int sperm = (((lane & 7) ^ srow) << 3);
    const u16* aB = Wqb + ((size_t)(j0 + w * 32 + srow) << 8) + sperm;
    const u16* bB = XT + ((size_t)(b * N_ + n0 + w * 32 + srow) << 8) + sperm;
    int rdp = ((lm & 7) << 3);
    f32x4 acc[4][4] = {};
    auto stg = [&](int p, int kc) {
#pragma unroll
        for (int i = 0; i < 4; ++i) {
            gld16(aB + i * 2048 + kc * 64, &As[p][w * 2048 + i * 512]);
            gld16(bB + i * 2048 + kc * 64, &Bs[p][w * 2048 + i * 512]);
        }
    };
    stg(0, 0);
#pragma unroll
    for (int kt = 0; kt < 4; ++kt) {
        int p = kt & 1;
        __syncthreads();
        if (kt < 3) stg(p ^ 1, kt + 1);
#pragma unroll
        for (int c2 = 0; c2 < 2; ++c2) {
            frag16 af[4], bf[4];
#pragma unroll
            for (int i = 0; i < 4; ++i)
                af[i] = *(const frag16*)&As[p][(wm * 64 + i * 16 + lm) * 64 + ((((c2 * 4 + qm) << 3) ^ rdp))];
#pragma unroll
            for (int j = 0; j < 4; ++j)
                bf[j] = *(const frag16*)&Bs[p][(wn * 64 + j * 16 + lm) * 64 + ((((c2 * 4 + qm) << 3) ^ rdp))];
#pragma unroll
            for (int i = 0; i < 4; ++i)
#pragma unroll
                for (int j = 0; j < 4; ++j)
                    acc[i][j] = __builtin_amdgcn_mfma_f32_16x16x32_bf16(af[i], bf[j], acc[i][j], 0, 0, 0);
        }
    }
    u16* To = Tb + ((size_t)b * 768 + j0 + wm * 64) * N_ + n0 + wn * 64;
#pragma unroll
    for (int i = 0; i < 4; ++i)
#pragma unroll
        for (int j = 0; j < 4; ++j)
#pragma unroll
            for (int r = 0; r < 4; ++r)
                To[(size_t)(i * 16 + qm * 4 + r) * N_ + j * 16 + lm] = f2bf(acc[i][j][r]);
    if (j0 < 512) {   // q,k rows: accumulate sum-of-squares per row
#pragma unroll
        for (int i = 0; i < 4; ++i)
#pragma unroll
            for (int r = 0; r < 4; ++r) {
                float s = 0.f;
#pragma unroll
                for (int j = 0; j < 4; ++j) s += acc[i][j][r] * acc[i][j][r];
                s += __shfl_xor(s, 1); s += __shfl_xor(s, 2);
                s += __shfl_xor(s, 4); s += __shfl_xor(s, 8);
                if (lm == 0)
                    atomicAdd(&RSQ[b * 512 + j0 + wm * 64 + i * 16 + qm * 4 + r], s);
            }
    }
}

// ================ ca score partials over 32 n-slices: SP[b][h][s][d*32+e] ================
__global__ __launch_bounds__(256) void k_ca_part(const u16* __restrict__ Tb, float* __restrict__ SP) {
    int s = blockIdx.x, h = blockIdx.y, b = blockIdx.z;
    int t = threadIdx.x, d = t & 31, eg = t >> 5;
    const u16* Q  = Tb + ((size_t)b * 768 + h * 32 + d) * N_ + s * 128;
    const u16* K0 = Tb + ((size_t)b * 768 + 256 + h * 32 + eg * 4) * N_ + s * 128;
    float a0 = 0.f, a1 = 0.f, a2 = 0.f, a3 = 0.f;
    for (int u = 0; u < 128; u += 8) {
        uint4 qv = *(const uint4*)(Q + u);
        uint4 k0 = *(const uint4*)(K0 + u);
        uint4 k1 = *(const uint4*)(K0 + (size_t)N_ + u);
        uint4 k2 = *(const uint4*)(K0 + (size_t)2 * N_ + u);
        uint4 k3 = *(const uint4*)(K0 + (size_t)3 * N_ + u);
        const u16 *qh = (const u16*)&qv, *h0 = (const u16*)&k0, *h1 = (const u16*)&k1,
                  *h2 = (const u16*)&k2, *h3 = (const u16*)&k3;
#pragma unroll
        for (int i = 0; i < 8; ++i) {
            float qf = bb(qh[i]);
            a0 += qf * bb(h0[i]); a1 += qf * bb(h1[i]);
            a2 += qf * bb(h2[i]); a3 += qf * bb(h3[i]);
        }
    }
    float* o = SP + (((size_t)(b * NH + h)) * 32 + s) * 1024 + d * 32 + eg * 4;
    o[0] = a0; o[1] = a1; o[2] = a2; o[3] = a3;
}

// ================ ca: sum partials, scale by 1/(||q|| ||k||), softmax, apply ================
__global__ __launch_bounds__(256) void k_ca_apply(const u16* __restrict__ Tb, const float* __restrict__ SP,
                                                  const float* __restrict__ RSQ, u16* __restrict__ XCAb) {
    int n0 = blockIdx.x * 256, h = blockIdx.y, b = blockIdx.z;
    __shared__ float raw[1024];
    __shared__ float Ae[32][32];   // [e][d]
    __shared__ float sq[32], sk[32];
    int tid = threadIdx.x;
    const float* Sp = SP + ((size_t)(b * NH + h)) * 32768;
    for (int u = tid; u < 1024; u += 256) {
        float v = 0.f;
#pragma unroll
        for (int s = 0; s < 32; ++s) v += Sp[s * 1024 + u];
        raw[u] = v;
    }
    if (tid < 32) {
        sq[tid] = 1.0f / fmaxf(sqrtf(RSQ[b * 512 + h * 32 + tid]), 1e-12f);
        sk[tid] = 1.0f / fmaxf(sqrtf(RSQ[b * 512 + 256 + h * 32 + tid]), 1e-12f);
    }
    __syncthreads();
    if (tid < 32) {                 // row d = tid
        float iq = sq[tid];
        float sv[32]; float m = -1e30f;
#pragma unroll
        for (int e = 0; e < 32; ++e) { sv[e] = raw[tid * 32 + e] * iq * sk[e]; m = fmaxf(m, sv[e]); }
        float sm = 0.f;
#pragma unroll
        for (int e = 0; e < 32; ++e) { sv[e] = __expf(sv[e] - m); sm += sv[e]; }
        float rinv = 1.0f / sm;
#pragma unroll
        for (int e = 0; e < 32; ++e) Ae[e][tid] = sv[e] * rinv;
    }
    __syncthreads();
    int n = n0 + tid;
    const u16* V = Tb + ((size_t)b * 768 + 512 + h * 32) * N_ + n;
    float acc[32];
#pragma unroll
    for (int d = 0; d < 32; ++d) acc[d] = 0.f;
#pragma unroll
    for (int e = 0; e < 32; ++e) {
        float v = bb(V[(size_t)e * N_]);
#pragma unroll
        for (int dg = 0; dg < 8; ++dg) {
            float4 a4 = *(const float4*)&Ae[e][dg * 4];
            acc[dg * 4 + 0] += a4.x * v; acc[dg * 4 + 1] += a4.y * v;
            acc[dg * 4 + 2] += a4.z * v; acc[dg * 4 + 3] += a4.w * v;
        }
    }
    u16* o = XCAb + ((size_t)b * N_ + n) * C_ + h * 32;
#pragma unroll
    for (int dg = 0; dg < 8; ++dg) {
        ushort4 pk;
        pk.x = f2bf(acc[dg * 4 + 0]); pk.y = f2bf(acc[dg * 4 + 1]);
        pk.z = f2bf(acc[dg * 4 + 2]); pk.w = f2bf(acc[dg * 4 + 3]);
        *(ushort4*)(o + dg * 4) = pk;
    }
}

// ================ out2 MFMA + residual -> ATTb bf16 [c][n], ATTp bf16 [n_pad][c] ================
__global__ __launch_bounds__(256) void k_out2_mfma(const u16* __restrict__ W2B, const u16* __restrict__ XCAb,
                                                   const float* __restrict__ bias2, const float* __restrict__ g1,
                                                   const float* __restrict__ X, u16* __restrict__ ATTb,
                                                   u16* __restrict__ ATTp) {
    __shared__ __align__(16) u16 As[2][8192], Bs[2][8192];
    int n0 = blockIdx.x * 128, c0 = blockIdx.y * 128, b = blockIdx.z;
    int tid = threadIdx.x, lane = tid & 63, w = tid >> 6;
    int wm = w & 1, wn = w >> 1, qm = lane >> 4, lm = lane & 15;
    int srow = lane >> 3;
    int sperm = (((lane & 7) ^ srow) << 3);
    const u16* aB = W2B + ((size_t)(c0 + w * 32 + srow) << 8) + sperm;
    const u16* bB = XCAb + ((size_t)(b * N_ + n0 + w * 32 + srow) << 8) + sperm;
    int rdp = ((lm & 7) << 3);
    f32x4 acc[4][4] = {};
    auto stg = [&](int p, int kc) {
#pragma unroll
        for (int i = 0; i < 4; ++i) {
            gld16(aB + i * 2048 + kc * 64, &As[p][w * 2048 + i * 512]);
            gld16(bB + i * 2048 + kc * 64, &Bs[p][w * 2048 + i * 512]);
        }
    };
    stg(0, 0);
#pragma unroll
    for (int kt = 0; kt < 4; ++kt) {
        int p = kt & 1;
        __syncthreads();
        if (kt < 3) stg(p ^ 1, kt + 1);
#pragma unroll
        for (int c2 = 0; c2 < 2; ++c2) {
            frag16 af[4], bf[4];
#pragma unroll
            for (int i = 0; i < 4; ++i)
                af[i] = *(const frag16*)&As[p][(wm * 64 + i * 16 + lm) * 64 + ((((c2 * 4 + qm) << 3) ^ rdp))];
#pragma unroll
            for (int j = 0; j < 4; ++j)
                bf[j] = *(const frag16*)&Bs[p][(wn * 64 + j * 16 + lm) * 64 + ((((c2 * 4 + qm) << 3) ^ rdp))];
#pragma unroll
            for (int i = 0; i < 4; ++i)
#pragma unroll
                for (int j = 0; j < 4; ++j)
                    acc[i][j] = __builtin_amdgcn_mfma_f32_16x16x32_bf16(af[i], bf[j], acc[i][j], 0, 0, 0);
        }
    }
    int c_base = c0 + wm * 64, n_base = n0 + wn * 64;
    const float* xin = X + (size_t)b * CN;
    u16* Ao = ATTb + (size_t)b * CN;
    u16* Ap = ATTp + ((size_t)b * PADV << 8);
    float val[4][4][4];
#pragma unroll
    for (int i = 0; i < 4; ++i)
#pragma unroll
        for (int r = 0; r < 4; ++r) {
            int c = c_base + i * 16 + qm * 4 + r;
            float gv = g1[c], bi = bias2[c];
#pragma unroll
            for (int j = 0; j < 4; ++j) {
                int n = n_base + j * 16 + lm;
                float v = xin[(size_t)c * N_ + n] + gv * (acc[i][j][r] + bi);
                val[i][j][r] = v;
                Ao[(size_t)c * N_ + n] = f2bf(v);
            }
        }
#pragma unroll
    for (int j = 0; j < 4; ++j) {
        int n = n_base + j * 16 + lm;
        int pr = padrow(n);
#pragma unroll
        for (int i = 0; i < 4; ++i) {
            ushort4 pk;
            pk.x = f2bf(val[i][j][0]); pk.y = f2bf(val[i][j][1]);
            pk.z = f2bf(val[i][j][2]); pk.w = f2bf(val[i][j][3]);
            *(ushort4*)&Ap[((size_t)pr << 8) + c_base + i * 16 + qm * 4] = pk;
        }
    }
}

// ================ conv 3^3 MFMA, split-K=3, K=64 chunks, bf16 partials ================
__global__ __launch_bounds__(256) void k_conv_mfma(const u16* __restrict__ WT2, const u16* __restrict__ ATTp,
                                                   u16* __restrict__ Pk) {
    __shared__ __align__(16) u16 As[2][8192], Bs[2][8192];
    int n0 = blockIdx.x * 128;
    int co0 = (blockIdx.y & 1) * 128, ks = blockIdx.y >> 1;
    int b = blockIdx.z;
    int tid = threadIdx.x, lane = tid & 63, w = tid >> 6;
    int wm = w & 1, wn = w >> 1, qm = lane >> 4, lm = lane & 15;
    int srow = lane >> 3;
    int sperm = (((lane & 7) ^ srow) << 3);
    const u16* aB = WT2 + (((size_t)ks * 9 * 256 + co0 + w * 32 + srow) << 8) + sperm;
    int prA[4];
#pragma unroll
    for (int i = 0; i < 4; ++i) prA[i] = padrow(n0 + w * 32 + i * 8 + srow) << 8;
    const u16* bB = ATTp + ((size_t)b * PADV << 8) + ((ks - 1) * 324 << 8) + sperm;
    int rdp = ((lm & 7) << 3);
    f32x4 acc[4][4] = {};
    auto stg = [&](int p, int kt) {
        int tap9 = kt >> 2, kc = kt & 3;
        int K9 = ((tap9 / 3) - 1) * 18 + (tap9 % 3 - 1);   // constant-folds under full unroll
#pragma unroll
        for (int i = 0; i < 4; ++i) {
            gld16(aB + (size_t)tap9 * 65536 + i * 2048 + kc * 64, &As[p][w * 2048 + i * 512]);
            gld16(bB + prA[i] + K9 * 256 + kc * 64,              &Bs[p][w * 2048 + i * 512]);
        }
    };
    stg(0, 0);
#pragma unroll
    for (int kt = 0; kt < 36; ++kt) {
        int p = kt & 1;
        __syncthreads();
        if (kt < 35) stg(p ^ 1, kt + 1);
#pragma unroll
        for (int c2 = 0; c2 < 2; ++c2) {
            frag16 af[4], bf[4];
#pragma unroll
            for (int i = 0; i < 4; ++i)
                af[i] = *(const frag16*)&As[p][(wm * 64 + i * 16 + lm) * 64 + ((((c2 * 4 + qm) << 3) ^ rdp))];
#pragma unroll
            for (int j = 0; j < 4; ++j)
                bf[j] = *(const frag16*)&Bs[p][(wn * 64 + j * 16 + lm) * 64 + ((((c2 * 4 + qm) << 3) ^ rdp))];
#pragma unroll
            for (int i = 0; i < 4; ++i)
#pragma unroll
                for (int j = 0; j < 4; ++j)
                    acc[i][j] = __builtin_amdgcn_mfma_f32_16x16x32_bf16(af[i], bf[j], acc[i][j], 0, 0, 0);
        }
    }
    u16* Pb = Pk + ((size_t)(ks * B_ + b) * C_ + co0 + wm * 64) * N_ + n0 + wn * 64;
#pragma unroll
    for (int i = 0; i < 4; ++i)
#pragma unroll
        for (int j = 0; j < 4; ++j)
#pragma unroll
            for (int r = 0; r < 4; ++r)
                Pb[(size_t)(i * 16 + qm * 4 + r) * N_ + j * 16 + lm] = f2bf(acc[i][j][r]);
}

// ================ combine bf16 split-K -> bf16 Y + batch mean/var partials ================
__global__ __launch_bounds__(256) void k_gn_reduce(const u16* __restrict__ Pk, u16* __restrict__ Y,
                                                   float* __restrict__ RED) {
    int blk = blockIdx.x, b = blockIdx.y;
    size_t base = (size_t)b * CN + (size_t)blk * 16384;
    const u16* p0 = Pk + base;
    const u16* p1 = Pk + BCN + base;
    const u16* p2 = Pk + (size_t)2 * BCN + base;
    u16* y = Y + base;
    float s = 0.f, q = 0.f;
    for (int u = threadIdx.x * 8; u < 16384; u += 2048) {
        uint4 a = *(const uint4*)&p0[u];
        uint4 c1 = *(const uint4*)&p1[u];
        uint4 c2 = *(const uint4*)&p2[u];
        const u16 *A = (const u16*)&a, *B1 = (const u16*)&c1, *C2 = (const u16*)&c2;
        __align__(16) u16 outp[8];
#pragma unroll
        for (int i = 0; i < 8; ++i) {
            float v = bb(A[i]) + bb(B1[i]) + bb(C2[i]);
            s += v; q += v * v;
            outp[i] = f2bf(v);
        }
        *(uint4*)&y[u] = *(const uint4*)outp;
    }
#pragma unroll
    for (int off = 32; off; off >>= 1) { s += __shfl_down(s, off); q += __shfl_down(q, off); }
    __shared__ float rs_[4], rq[4];
    int lane = threadIdx.x & 63, wv = threadIdx.x >> 6;
    if (!lane) { rs_[wv] = s; rq[wv] = q; }
    __syncthreads();
    if (threadIdx.x == 0) {
        RED[((size_t)b * 64 + blk) * 2 + 0] = rs_[0] + rs_[1] + rs_[2] + rs_[3];
        RED[((size_t)b * 64 + blk) * 2 + 1] = rq[0] + rq[1] + rq[2] + rq[3];
    }
}

// ================ finalize: RED reduce + normalize + residual + leaky relu ================
__global__ __launch_bounds__(256) void k_final(const u16* __restrict__ Y, const u16* __restrict__ ATTb,
                                               const float* __restrict__ RED, const float* __restrict__ gw,
                                               const float* __restrict__ gb, float* __restrict__ out) {
    int i = blockIdx.x * 256 + threadIdx.x;
    int b = i >> 20;
    int c = (i >> 12) & 255;
    __shared__ float smu[2];
    if (threadIdx.x < 64) {
        float s = RED[((size_t)b * 64 + threadIdx.x) * 2 + 0];
        float q = RED[((size_t)b * 64 + threadIdx.x) * 2 + 1];
#pragma unroll
        for (int off = 32; off; off >>= 1) { s += __shfl_down(s, off); q += __shfl_down(q, off); }
        if (threadIdx.x == 0) {
            float inv = 1.0f / (float)CN;
            float mu = s * inv, var = q * inv - mu * mu;
            smu[0] = mu; smu[1] = rsqrtf(var + 1e-5f);
        }
    }
    __syncthreads();
    float v = (bb(Y[i]) - smu[0]) * smu[1] * gw[c] + gb[c] + bb(ATTb[i]);
    out[i] = v >= 0.f ? v : 0.01f * v;
}

extern "C" void kernel_launch(void* const* d_in, const int* in_sizes, int n_in,
                              void* d_out, int out_size, void* d_ws, size_t ws_size,
                              hipStream_t stream) {
    const float* x      = (const float*)d_in[0];
    const float* Wqkvv  = (const float*)d_in[1];
    // d_in[2] W_out, d_in[3] b_out, d_in[10] index_sample: DEAD in reference
    const float* W_out2 = (const float*)d_in[4];
    const float* b_out2 = (const float*)d_in[5];
    const float* gamma1 = (const float*)d_in[6];
    const float* conv_w = (const float*)d_in[7];
    const float* gn_w   = (const float*)d_in[8];
    const float* gn_b   = (const float*)d_in[9];
    float* out = (float*)d_out;
    float* ws = (float*)d_ws;

    u16*   Tb   = (u16*)(ws + OFF_TB);
    float* SP   = ws + OFF_SP;
    u16*   XCAb = (u16*)(ws + OFF_XCAB);
    u16*   Pk   = (u16*)(ws + OFF_PKB);   // aliases Tb (dead before conv)
    u16*   Y    = (u16*)(ws + OFF_Y);     // aliases SP/XCAb head (dead before gn_reduce)
    u16*   ATTb = (u16*)(ws + OFF_ATTB);
    u16*   ATTp = (u16*)(ws + OFF_ATTP);
    u16*   WT2  = (u16*)(ws + OFF_WT2);
    u16*   W2B  = (u16*)(ws + OFF_W2B);
    u16*   Wqb  = (u16*)(ws + OFF_WQB);
    u16*   XT   = (u16*)(ws + OFF_XT);
    float* RSQ  = ws + OFF_RSQ;
    float* RED  = ws + OFF_RED;

    k_prep      <<<8393, 256, 0, stream>>>(conv_w, W_out2, Wqkvv, x, WT2, W2B, Wqb, XT, (u32*)ATTp, RSQ);
    k_qkv_mfma  <<<dim3(N_ / 128, 6, B_), 256, 0, stream>>>(Wqb, XT, Tb, RSQ);
    k_ca_part   <<<dim3(32, NH, B_), 256, 0, stream>>>(Tb, SP);
    k_ca_apply  <<<dim3(N_ / 256, NH, B_), 256, 0, stream>>>(Tb, SP, RSQ, XCAb);
    k_out2_mfma <<<dim3(N_ / 128, C_ / 128, B_), 256, 0, stream>>>(W2B, XCAb, b_out2, gamma1, x, ATTb, ATTp);
    k_conv_mfma <<<dim3(N_ / 128, 6, B_), 256, 0, stream>>>(WT2, ATTp, Pk);
    k_gn_reduce <<<dim3(64, B_), 256, 0, stream>>>(Pk, Y, RED);
    k_final     <<<(B_ * CN) / 256, 256, 0, stream>>>(Y, ATTb, RED, gn_w, gn_b, out);
}

// Round 7
// 174.071 us; speedup vs baseline: 5.4076x; 1.0410x over previous
//
#include <hip/hip_runtime.h>
#include <hip/hip_bf16.h>
#include <stdint.h>

// B=2, C=256, H=W=D=16 -> N=4096, nh=8, dh=32. ALL float32 I/O.
// Reference dead code: x_sa path (top-k, index_sample, W_out, b_out, v_sa) — epa = x_ca only.
// Round 7: ca scores via MFMA (coalesced gld16 staging) replacing the uncoalesced
// per-lane row gather; prep XT transpose retiled 64x64.

#define B_ 2
#define C_ 256
#define N_ 4096
#define NH 8
#define PADV 5832
#define CN  (C_*N_)
#define BCN (B_*CN)

typedef unsigned short u16;
typedef unsigned int   u32;

using frag16 = __attribute__((ext_vector_type(8))) short;
using f32x4  = __attribute__((ext_vector_type(4))) float;

__device__ __forceinline__ u16 f2bf(float f) {
    u32 u = __float_as_uint(f);
    u += 0x7fff + ((u >> 16) & 1);
    return (u16)(u >> 16);
}
__device__ __forceinline__ float bb(u16 h) { return __uint_as_float((u32)h << 16); }
__device__ __forceinline__ void gld16(const void* g, void* l) {
    __builtin_amdgcn_global_load_lds((const __attribute__((address_space(1))) u32*)g,
                                     (__attribute__((address_space(3))) u32*)l, 16, 0, 0);
}
__device__ __forceinline__ int padrow(int n) {
    int z = n >> 8, y = (n >> 4) & 15, x = n & 15;
    return (z + 1) * 324 + (y + 1) * 18 + (x + 1);
}

// ---- workspace (float units)
#define OFF_TB    0            // bf16 [B][768][N]; aliased by PKB after ca_apply
#define OFF_SP    3145728      // fp32 [B][NH][8][1024] score partials (dead after ca_apply)
#define OFF_XCAB  3670016      // bf16 [B][N][C]
#define OFF_PKB   0            // bf16 [3][B][C][N] conv partials (alias TB)
#define OFF_Y     3145728      // bf16 [B][C][N] (alias SP/XCAB head, both dead)
#define OFF_ATTB  6291456      // bf16 [B][C][N]
#define OFF_ATTP  7340032      // bf16 [B][PADV][C]
#define OFF_WT2   8833024      // bf16 [27][co][ci]
#define OFF_W2B   9717760      // bf16 [c][c']
#define OFF_WQB   9750528      // bf16 [j][c], j<768
#define OFF_XT    9848832      // bf16 [B][N][C]
#define OFF_RSQ   10897408     // fp32 [B][512]
#define OFF_RED   10898432     // fp32 [B][64][2]

// ================ merged prep ================
__global__ __launch_bounds__(256) void k_prep(const float* __restrict__ CW, const float* __restrict__ W2,
                                              const float* __restrict__ Wq, const float* __restrict__ X,
                                              u16* __restrict__ WT2, u16* __restrict__ W2B,
                                              u16* __restrict__ Wqb, u16* __restrict__ XT,
                                              u32* __restrict__ APz, float* __restrict__ RSQ) {
    __shared__ __align__(16) float ls[6912];
    float (*ts)[33] = (float(*)[33])ls;
    float (*t64)[65] = (float(*)[65])ls;
    int blk = blockIdx.x, tid = threadIdx.x;
    if (blk < 256) {                                    // WT2[t][co][ci] = conv_w[co][ci][t]
        int co = blk;
        const float* src = CW + (size_t)co * 6912;
        for (int u = tid; u < 6912; u += 256) ls[u] = src[u];
        __syncthreads();
#pragma unroll
        for (int t = 0; t < 27; ++t)
            WT2[(((size_t)t * 256 + co) << 8) + tid] = f2bf(ls[tid * 27 + t]);
    } else if (blk < 320) {                             // W2B[c][p] = W2[p][c]
        int bi = blk - 256; int c0 = (bi & 7) * 32, p0 = (bi >> 3) * 32;
        int tx = tid & 31, ty = tid >> 5;
#pragma unroll
        for (int i = 0; i < 4; ++i) ts[ty + i * 8][tx] = W2[(size_t)(p0 + ty + i * 8) * 256 + c0 + tx];
        __syncthreads();
#pragma unroll
        for (int i = 0; i < 4; ++i) W2B[(size_t)(c0 + ty + i * 8) * 256 + p0 + tx] = f2bf(ts[tx][ty + i * 8]);
    } else if (blk < 512) {                             // Wqb[j][c] = Wq[c][j], j<768
        int bi = blk - 320; int c0 = (bi & 7) * 32, j0 = (bi >> 3) * 32;
        int tx = tid & 31, ty = tid >> 5;
#pragma unroll
        for (int i = 0; i < 4; ++i) ts[ty + i * 8][tx] = Wq[(size_t)(c0 + ty + i * 8) * 1024 + j0 + tx];
        __syncthreads();
#pragma unroll
        for (int i = 0; i < 4; ++i) Wqb[(size_t)(j0 + ty + i * 8) * 256 + c0 + tx] = f2bf(ts[tx][ty + i * 8]);
    } else if (blk < 1024) {                            // XT[b][n][c] = x[b][c][n], 64x64 tiles
        int idx = blk - 512;
        int n0 = (idx & 63) * 64, c0 = ((idx >> 6) & 3) * 64, b = idx >> 8;
        int tn = tid & 63, tc4 = tid >> 6;
        const float* Xb = X + (size_t)b * CN;
#pragma unroll
        for (int i = 0; i < 16; ++i) t64[tc4 + i * 4][tn] = Xb[(size_t)(c0 + tc4 + i * 4) * N_ + n0 + tn];
        __syncthreads();
        u16* Xo = XT + (size_t)b * N_ * C_;
#pragma unroll
        for (int i = 0; i < 16; ++i)
            Xo[(size_t)(n0 + tc4 + i * 4) * C_ + c0 + tn] = f2bf(t64[tn][tc4 + i * 4]);
    } else if (blk < 6856) {                            // zero ATTp
        APz[(size_t)(blk - 1024) * 256 + tid] = 0;
    } else {                                            // zero RSQ
        ((float4*)RSQ)[tid] = make_float4(0.f, 0.f, 0.f, 0.f);
    }
}

// ================ QKV MFMA, K=64 chunks + RSQ row-sumsq atomics ================
__global__ __launch_bounds__(256) void k_qkv_mfma(const u16* __restrict__ Wqb, const u16* __restrict__ XT,
                                                  u16* __restrict__ Tb, float* __restrict__ RSQ) {
    __shared__ __align__(16) u16 As[2][8192], Bs[2][8192];
    int n0 = blockIdx.x * 128, j0 = blockIdx.y * 128, b = blockIdx.z;
    int tid = threadIdx.x, lane = tid & 63, w = tid >> 6;
    int wm = w & 1, wn = w >> 1, qm = lane >> 4, lm = lane & 15;
    int srow = lane >> 3;
    int sperm = (((lane & 7) ^ srow) << 3);
    const u16* aB = Wqb + ((size_t)(j0 + w * 32 + srow) << 8) + sperm;
    const u16* bB = XT + ((size_t)(b * N_ + n0 + w * 32 + srow) << 8) + sperm;
    int rdp = ((lm & 7) << 3);
    f32x4 acc[4][4] = {};
    auto stg = [&](int p, int kc) {
#pragma unroll
        for (int i = 0; i < 4; ++i) {
            gld16(aB + i * 2048 + kc * 64, &As[p][w * 2048 + i * 512]);
            gld16(bB + i * 2048 + kc * 64, &Bs[p][w * 2048 + i * 512]);
        }
    };
    stg(0, 0);
#pragma unroll
    for (int kt = 0; kt < 4; ++kt) {
        int p = kt & 1;
        __syncthreads();
        if (kt < 3) stg(p ^ 1, kt + 1);
#pragma unroll
        for (int c2 = 0; c2 < 2; ++c2) {
            frag16 af[4], bf[4];
#pragma unroll
            for (int i = 0; i < 4; ++i)
                af[i] = *(const frag16*)&As[p][(wm * 64 + i * 16 + lm) * 64 + ((((c2 * 4 + qm) << 3) ^ rdp))];
#pragma unroll
            for (int j = 0; j < 4; ++j)
                bf[j] = *(const frag16*)&Bs[p][(wn * 64 + j * 16 + lm) * 64 + ((((c2 * 4 + qm) << 3) ^ rdp))];
#pragma unroll
            for (int i = 0; i < 4; ++i)
#pragma unroll
                for (int j = 0; j < 4; ++j)
                    acc[i][j] = __builtin_amdgcn_mfma_f32_16x16x32_bf16(af[i], bf[j], acc[i][j], 0, 0, 0);
        }
    }
    u16* To = Tb + ((size_t)b * 768 + j0 + wm * 64) * N_ + n0 + wn * 64;
#pragma unroll
    for (int i = 0; i < 4; ++i)
#pragma unroll
        for (int j = 0; j < 4; ++j)
#pragma unroll
            for (int r = 0; r < 4; ++r)
                To[(size_t)(i * 16 + qm * 4 + r) * N_ + j * 16 + lm] = f2bf(acc[i][j][r]);
    if (j0 < 512) {
#pragma unroll
        for (int i = 0; i < 4; ++i)
#pragma unroll
            for (int r = 0; r < 4; ++r) {
                float s = 0.f;
#pragma unroll
                for (int j = 0; j < 4; ++j) s += acc[i][j][r] * acc[i][j][r];
                s += __shfl_xor(s, 1); s += __shfl_xor(s, 2);
                s += __shfl_xor(s, 4); s += __shfl_xor(s, 8);
                if (lm == 0)
                    atomicAdd(&RSQ[b * 512 + j0 + wm * 64 + i * 16 + qm * 4 + r], s);
            }
    }
}

// ================ CA scores via MFMA: SP[b][h][ks][d*32+e] = sum_{k in slice} q[d][k] k[e][k] =====
__global__ __launch_bounds__(256) void k_ca_score(const u16* __restrict__ Tb, float* __restrict__ SP) {
    __shared__ __align__(16) u16 Qs[2][8192], Ks[2][8192];   // 32 rows x 256 u16, XOR-swizzled chunks
    int ks = blockIdx.x, h = blockIdx.y, b = blockIdx.z;
    int tid = threadIdx.x, lane = tid & 63, w = tid >> 6;
    int wm = w & 1, wn = w >> 1, qm = lane >> 4, lm = lane & 15;
    const u16* Qb = Tb + ((size_t)b * 768 + h * 32) * N_;
    const u16* Kb = Tb + ((size_t)b * 768 + 256 + h * 32) * N_;
    int k0base = ks * 512;
    // staging: LDS slot cs of row holds global chunk cs ^ (row&31); dest auto = base + lane*16
    auto stg = [&](int p, int ck) {
        int k0 = k0base + ck * 256;
#pragma unroll
        for (int ri = 0; ri < 4; ++ri) {
            int row = ri * 8 + w * 2 + (lane >> 5);
            int cg = (lane & 31) ^ (row & 31);
            gld16(Qb + (size_t)row * N_ + k0 + cg * 8, &Qs[p][ri * 2048 + w * 512]);
            gld16(Kb + (size_t)row * N_ + k0 + cg * 8, &Ks[p][ri * 2048 + w * 512]);
        }
    };
    f32x4 acc = {};
    stg(0, 0);
#pragma unroll
    for (int ck = 0; ck < 2; ++ck) {
        int p = ck & 1;
        __syncthreads();
        if (ck < 1) stg(p ^ 1, ck + 1);
        int rowA = wm * 16 + lm, rowB = wn * 16 + lm;
#pragma unroll
        for (int kk = 0; kk < 8; ++kk) {
            int slotA = ((kk * 4 + qm) ^ (rowA & 31)) << 3;
            int slotB = ((kk * 4 + qm) ^ (rowB & 31)) << 3;
            frag16 af = *(const frag16*)&Qs[p][rowA * 256 + slotA];
            frag16 bf = *(const frag16*)&Ks[p][rowB * 256 + slotB];
            acc = __builtin_amdgcn_mfma_f32_16x16x32_bf16(af, bf, acc, 0, 0, 0);
        }
    }
    float* o = SP + (((size_t)(b * NH + h)) * 8 + ks) * 1024;
#pragma unroll
    for (int r = 0; r < 4; ++r)
        o[(wm * 16 + qm * 4 + r) * 32 + wn * 16 + lm] = acc[r];
}

// ================ ca: combine partials, scale by 1/(||q|| ||k||), softmax, apply ================
__global__ __launch_bounds__(256) void k_ca_apply(const u16* __restrict__ Tb, const float* __restrict__ SP,
                                                  const float* __restrict__ RSQ, u16* __restrict__ XCAb) {
    int n0 = blockIdx.x * 256, h = blockIdx.y, b = blockIdx.z;
    __shared__ float raw[1024];
    __shared__ float Ae[32][32];
    __shared__ float sq[32], sk[32];
    int tid = threadIdx.x;
    const float* Sp = SP + ((size_t)(b * NH + h)) * 8192;
    for (int u = tid; u < 1024; u += 256) {
        float v = 0.f;
#pragma unroll
        for (int s = 0; s < 8; ++s) v += Sp[s * 1024 + u];
        raw[u] = v;
    }
    if (tid < 32) {
        sq[tid] = 1.0f / fmaxf(sqrtf(RSQ[b * 512 + h * 32 + tid]), 1e-12f);
        sk[tid] = 1.0f / fmaxf(sqrtf(RSQ[b * 512 + 256 + h * 32 + tid]), 1e-12f);
    }
    __syncthreads();
    if (tid < 32) {
        float iq = sq[tid];
        float sv[32]; float m = -1e30f;
#pragma unroll
        for (int e = 0; e < 32; ++e) { sv[e] = raw[tid * 32 + e] * iq * sk[e]; m = fmaxf(m, sv[e]); }
        float sm = 0.f;
#pragma unroll
        for (int e = 0; e < 32; ++e) { sv[e] = __expf(sv[e] - m); sm += sv[e]; }
        float rinv = 1.0f / sm;
#pragma unroll
        for (int e = 0; e < 32; ++e) Ae[e][tid] = sv[e] * rinv;
    }
    __syncthreads();
    int n = n0 + tid;
    const u16* V = Tb + ((size_t)b * 768 + 512 + h * 32) * N_ + n;
    float acc[32];
#pragma unroll
    for (int d = 0; d < 32; ++d) acc[d] = 0.f;
#pragma unroll
    for (int e = 0; e < 32; ++e) {
        float v = bb(V[(size_t)e * N_]);
#pragma unroll
        for (int dg = 0; dg < 8; ++dg) {
            float4 a4 = *(const float4*)&Ae[e][dg * 4];
            acc[dg * 4 + 0] += a4.x * v; acc[dg * 4 + 1] += a4.y * v;
            acc[dg * 4 + 2] += a4.z * v; acc[dg * 4 + 3] += a4.w * v;
        }
    }
    u16* o = XCAb + ((size_t)b * N_ + n) * C_ + h * 32;
#pragma unroll
    for (int dg = 0; dg < 8; ++dg) {
        ushort4 pk;
        pk.x = f2bf(acc[dg * 4 + 0]); pk.y = f2bf(acc[dg * 4 + 1]);
        pk.z = f2bf(acc[dg * 4 + 2]); pk.w = f2bf(acc[dg * 4 + 3]);
        *(ushort4*)(o + dg * 4) = pk;
    }
}

// ================ out2 MFMA + residual -> ATTb bf16 [c][n], ATTp bf16 [n_pad][c] ================
__global__ __launch_bounds__(256) void k_out2_mfma(const u16* __restrict__ W2B, const u16* __restrict__ XCAb,
                                                   const float* __restrict__ bias2, const float* __restrict__ g1,
                                                   const float* __restrict__ X, u16* __restrict__ ATTb,
                                                   u16* __restrict__ ATTp) {
    __shared__ __align__(16) u16 As[2][8192], Bs[2][8192];
    int n0 = blockIdx.x * 128, c0 = blockIdx.y * 128, b = blockIdx.z;
    int tid = threadIdx.x, lane = tid & 63, w = tid >> 6;
    int wm = w & 1, wn = w >> 1, qm = lane >> 4, lm = lane & 15;
    int srow = lane >> 3;
    int sperm = (((lane & 7) ^ srow) << 3);
    const u16* aB = W2B + ((size_t)(c0 + w * 32 + srow) << 8) + sperm;
    const u16* bB = XCAb + ((size_t)(b * N_ + n0 + w * 32 + srow) << 8) + sperm;
    int rdp = ((lm & 7) << 3);
    f32x4 acc[4][4] = {};
    auto stg = [&](int p, int kc) {
#pragma unroll
        for (int i = 0; i < 4; ++i) {
            gld16(aB + i * 2048 + kc * 64, &As[p][w * 2048 + i * 512]);
            gld16(bB + i * 2048 + kc * 64, &Bs[p][w * 2048 + i * 512]);
        }
    };
    stg(0, 0);
#pragma unroll
    for (int kt = 0; kt < 4; ++kt) {
        int p = kt & 1;
        __syncthreads();
        if (kt < 3) stg(p ^ 1, kt + 1);
#pragma unroll
        for (int c2 = 0; c2 < 2; ++c2) {
            frag16 af[4], bf[4];
#pragma unroll
            for (int i = 0; i < 4; ++i)
                af[i] = *(const frag16*)&As[p][(wm * 64 + i * 16 + lm) * 64 + ((((c2 * 4 + qm) << 3) ^ rdp))];
#pragma unroll
            for (int j = 0; j < 4; ++j)
                bf[j] = *(const frag16*)&Bs[p][(wn * 64 + j * 16 + lm) * 64 + ((((c2 * 4 + qm) << 3) ^ rdp))];
#pragma unroll
            for (int i = 0; i < 4; ++i)
#pragma unroll
                for (int j = 0; j < 4; ++j)
                    acc[i][j] = __builtin_amdgcn_mfma_f32_16x16x32_bf16(af[i], bf[j], acc[i][j], 0, 0, 0);
        }
    }
    int c_base = c0 + wm * 64, n_base = n0 + wn * 64;
    const float* xin = X + (size_t)b * CN;
    u16* Ao = ATTb + (size_t)b * CN;
    u16* Ap = ATTp + ((size_t)b * PADV << 8);
    float val[4][4][4];
#pragma unroll
    for (int i = 0; i < 4; ++i)
#pragma unroll
        for (int r = 0; r < 4; ++r) {
            int c = c_base + i * 16 + qm * 4 + r;
            float gv = g1[c], bi = bias2[c];
#pragma unroll
            for (int j = 0; j < 4; ++j) {
                int n = n_base + j * 16 + lm;
                float v = xin[(size_t)c * N_ + n] + gv * (acc[i][j][r] + bi);
                val[i][j][r] = v;
                Ao[(size_t)c * N_ + n] = f2bf(v);
            }
        }
#pragma unroll
    for (int j = 0; j < 4; ++j) {
        int n = n_base + j * 16 + lm;
        int pr = padrow(n);
#pragma unroll
        for (int i = 0; i < 4; ++i) {
            ushort4 pk;
            pk.x = f2bf(val[i][j][0]); pk.y = f2bf(val[i][j][1]);
            pk.z = f2bf(val[i][j][2]); pk.w = f2bf(val[i][j][3]);
            *(ushort4*)&Ap[((size_t)pr << 8) + c_base + i * 16 + qm * 4] = pk;
        }
    }
}

// ================ conv 3^3 MFMA, split-K=3, K=64 chunks ================
__global__ __launch_bounds__(256) void k_conv_mfma(const u16* __restrict__ WT2, const u16* __restrict__ ATTp,
                                                   u16* __restrict__ Pk) {
    __shared__ __align__(16) u16 As[2][8192], Bs[2][8192];
    int n0 = blockIdx.x * 128;
    int co0 = (blockIdx.y & 1) * 128, ks = blockIdx.y >> 1;
    int b = blockIdx.z;
    int tid = threadIdx.x, lane = tid & 63, w = tid >> 6;
    int wm = w & 1, wn = w >> 1, qm = lane >> 4, lm = lane & 15;
    int srow = lane >> 3;
    int sperm = (((lane & 7) ^ srow) << 3);
    const u16* aB = WT2 + (((size_t)ks * 9 * 256 + co0 + w * 32 + srow) << 8) + sperm;
    int prA[4];
#pragma unroll
    for (int i = 0; i < 4; ++i) prA[i] = padrow(n0 + w * 32 + i * 8 + srow) << 8;
    const u16* bB = ATTp + ((size_t)b * PADV << 8) + ((ks - 1) * 324 << 8) + sperm;
    int rdp = ((lm & 7) << 3);
    f32x4 acc[4][4] = {};
    auto stg = [&](int p, int kt) {
        int tap9 = kt >> 2, kc = kt & 3;
        int K9 = ((tap9 / 3) - 1) * 18 + (tap9 % 3 - 1);
#pragma unroll
        for (int i = 0; i < 4; ++i) {
            gld16(aB + (size_t)tap9 * 65536 + i * 2048 + kc * 64, &As[p][w * 2048 + i * 512]);
            gld16(bB + prA[i] + K9 * 256 + kc * 64,              &Bs[p][w * 2048 + i * 512]);
        }
    };
    stg(0, 0);
#pragma unroll
    for (int kt = 0; kt < 36; ++kt) {
        int p = kt & 1;
        __syncthreads();
        if (kt < 35) stg(p ^ 1, kt + 1);
#pragma unroll
        for (int c2 = 0; c2 < 2; ++c2) {
            frag16 af[4], bf[4];
#pragma unroll
            for (int i = 0; i < 4; ++i)
                af[i] = *(const frag16*)&As[p][(wm * 64 + i * 16 + lm) * 64 + ((((c2 * 4 + qm) << 3) ^ rdp))];
#pragma unroll
            for (int j = 0; j < 4; ++j)
                bf[j] = *(const frag16*)&Bs[p][(wn * 64 + j * 16 + lm) * 64 + ((((c2 * 4 + qm) << 3) ^ rdp))];
#pragma unroll
            for (int i = 0; i < 4; ++i)
#pragma unroll
                for (int j = 0; j < 4; ++j)
                    acc[i][j] = __builtin_amdgcn_mfma_f32_16x16x32_bf16(af[i], bf[j], acc[i][j], 0, 0, 0);
        }
    }
    u16* Pb = Pk + ((size_t)(ks * B_ + b) * C_ + co0 + wm * 64) * N_ + n0 + wn * 64;
#pragma unroll
    for (int i = 0; i < 4; ++i)
#pragma unroll
        for (int j = 0; j < 4; ++j)
#pragma unroll
            for (int r = 0; r < 4; ++r)
                Pb[(size_t)(i * 16 + qm * 4 + r) * N_ + j * 16 + lm] = f2bf(acc[i][j][r]);
}

// ================ combine bf16 split-K -> bf16 Y + batch mean/var partials ================
__global__ __launch_bounds__(256) void k_gn_reduce(const u16* __restrict__ Pk, u16* __restrict__ Y,
                                                   float* __restrict__ RED) {
    int blk = blockIdx.x, b = blockIdx.y;
    size_t base = (size_t)b * CN + (size_t)blk * 16384;
    const u16* p0 = Pk + base;
    const u16* p1 = Pk + BCN + base;
    const u16* p2 = Pk + (size_t)2 * BCN + base;
    u16* y = Y + base;
    float s = 0.f, q = 0.f;
    for (int u = threadIdx.x * 8; u < 16384; u += 2048) {
        uint4 a = *(const uint4*)&p0[u];
        uint4 c1 = *(const uint4*)&p1[u];
        uint4 c2 = *(const uint4*)&p2[u];
        const u16 *A = (const u16*)&a, *B1 = (const u16*)&c1, *C2 = (const u16*)&c2;
        __align__(16) u16 outp[8];
#pragma unroll
        for (int i = 0; i < 8; ++i) {
            float v = bb(A[i]) + bb(B1[i]) + bb(C2[i]);
            s += v; q += v * v;
            outp[i] = f2bf(v);
        }
        *(uint4*)&y[u] = *(const uint4*)outp;
    }
#pragma unroll
    for (int off = 32; off; off >>= 1) { s += __shfl_down(s, off); q += __shfl_down(q, off); }
    __shared__ float rs_[4], rq[4];
    int lane = threadIdx.x & 63, wv = threadIdx.x >> 6;
    if (!lane) { rs_[wv] = s; rq[wv] = q; }
    __syncthreads();
    if (threadIdx.x == 0) {
        RED[((size_t)b * 64 + blk) * 2 + 0] = rs_[0] + rs_[1] + rs_[2] + rs_[3];
        RED[((size_t)b * 64 + blk) * 2 + 1] = rq[0] + rq[1] + rq[2] + rq[3];
    }
}

// ================ finalize ================
__global__ __launch_bounds__(256) void k_final(const u16* __restrict__ Y, const u16* __restrict__ ATTb,
                                               const float* __restrict__ RED, const float* __restrict__ gw,
                                               const float* __restrict__ gb, float* __restrict__ out) {
    int i = blockIdx.x * 256 + threadIdx.x;
    int b = i >> 20;
    int c = (i >> 12) & 255;
    __shared__ float smu[2];
    if (threadIdx.x < 64) {
        float s = RED[((size_t)b * 64 + threadIdx.x) * 2 + 0];
        float q = RED[((size_t)b * 64 + threadIdx.x) * 2 + 1];
#pragma unroll
        for (int off = 32; off; off >>= 1) { s += __shfl_down(s, off); q += __shfl_down(q, off); }
        if (threadIdx.x == 0) {
            float inv = 1.0f / (float)CN;
            float mu = s * inv, var = q * inv - mu * mu;
            smu[0] = mu; smu[1] = rsqrtf(var + 1e-5f);
        }
    }
    __syncthreads();
    float v = (bb(Y[i]) - smu[0]) * smu[1] * gw[c] + gb[c] + bb(ATTb[i]);
    out[i] = v >= 0.f ? v : 0.01f * v;
}

extern "C" void kernel_launch(void* const* d_in, const int* in_sizes, int n_in,
                              void* d_out, int out_size, void* d_ws, size_t ws_size,
                              hipStream_t stream) {
    const float* x      = (const float*)d_in[0];
    const float* Wqkvv  = (const float*)d_in[1];
    // d_in[2] W_out, d_in[3] b_out, d_in[10] index_sample: DEAD in reference
    const float* W_out2 = (const float*)d_in[4];
    const float* b_out2 = (const float*)d_in[5];
    const float* gamma1 = (const float*)d_in[6];
    const float* conv_w = (const float*)d_in[7];
    const float* gn_w   = (const float*)d_in[8];
    const float* gn_b   = (const float*)d_in[9];
    float* out = (float*)d_out;
    float* ws = (float*)d_ws;

    u16*   Tb   = (u16*)(ws + OFF_TB);
    float* SP   = ws + OFF_SP;
    u16*   XCAb = (u16*)(ws + OFF_XCAB);
    u16*   Pk   = (u16*)(ws + OFF_PKB);
    u16*   Y    = (u16*)(ws + OFF_Y);
    u16*   ATTb = (u16*)(ws + OFF_ATTB);
    u16*   ATTp = (u16*)(ws + OFF_ATTP);
    u16*   WT2  = (u16*)(ws + OFF_WT2);
    u16*   W2B  = (u16*)(ws + OFF_W2B);
    u16*   Wqb  = (u16*)(ws + OFF_WQB);
    u16*   XT   = (u16*)(ws + OFF_XT);
    float* RSQ  = ws + OFF_RSQ;
    float* RED  = ws + OFF_RED;

    k_prep      <<<6857, 256, 0, stream>>>(conv_w, W_out2, Wqkvv, x, WT2, W2B, Wqb, XT, (u32*)ATTp, RSQ);
    k_qkv_mfma  <<<dim3(N_ / 128, 6, B_), 256, 0, stream>>>(Wqb, XT, Tb, RSQ);
    k_ca_score  <<<dim3(8, NH, B_), 256, 0, stream>>>(Tb, SP);
    k_ca_apply  <<<dim3(N_ / 256, NH, B_), 256, 0, stream>>>(Tb, SP, RSQ, XCAb);
    k_out2_mfma <<<dim3(N_ / 128, C_ / 128, B_), 256, 0, stream>>>(W2B, XCAb, b_out2, gamma1, x, ATTb, ATTp);
    k_conv_mfma <<<dim3(N_ / 128, 6, B_), 256, 0, stream>>>(WT2, ATTp, Pk);
    k_gn_reduce <<<dim3(64, B_), 256, 0, stream>>>(Pk, Y, RED);
    k_final     <<<(B_ * CN) / 256, 256, 0, stream>>>(Y, ATTb, RED, gn_w, gn_b, out);
}